// Round 21
// baseline (164.574 us; speedup 1.0000x reference)
//
#include <hip/hip_runtime.h>
#include <hip/hip_bf16.h>
#include <math.h>

#define B_  2
#define S_  2048
#define H_  1024
#define NH_ 4
#define DH_ 256

typedef __attribute__((ext_vector_type(8))) short short8;
typedef __attribute__((ext_vector_type(4))) short short4v;
typedef __attribute__((ext_vector_type(4))) float f32x4;

#define KTILE_BYTES 16384   // 32 j x 256 d x 2B (swizzled slots)
#define VTILE_BYTES 18432   // 256 d x 36 shorts (transposed, swizzled, padded)

static __device__ __forceinline__ short f2bf(float x) {
  __hip_bfloat16 h = __float2bfloat16(x);
  union { __hip_bfloat16 h; short s; } u;
  u.h = h;
  return u.s;
}

static __device__ __forceinline__ float bf2f(short s) {
  union { unsigned u; float f; } t;
  t.u = ((unsigned)(unsigned short)s) << 16;
  return t.f;
}

static __device__ __forceinline__ short8 pack8(const float4& a, const float4& b) {
  short8 t;
  t[0] = f2bf(a.x); t[1] = f2bf(a.y); t[2] = f2bf(a.z); t[3] = f2bf(a.w);
  t[4] = f2bf(b.x); t[5] = f2bf(b.y); t[6] = f2bf(b.z); t[7] = f2bf(b.w);
  return t;
}

static __device__ __forceinline__ void gload16(const void* g, void* l) {
  __builtin_amdgcn_global_load_lds(
      (const __attribute__((address_space(1))) unsigned int*)g,
      (__attribute__((address_space(3))) unsigned int*)l, 16, 0, 0);
}
static __device__ __forceinline__ void gload4(const void* g, void* l) {
  __builtin_amdgcn_global_load_lds(
      (const __attribute__((address_space(1))) unsigned int*)g,
      (__attribute__((address_space(3))) unsigned int*)l, 4, 0, 0);
}

// ---------------------------------------------------------------------------
// Kernel 1: FUSED gates (blocks 0..4095 = B_*S_) + pack K/V (4096..4607).
// (R20 lesson: gates needs B_*S_=4096 blocks — b = bid/S_, not bid/2048.)
// ---------------------------------------------------------------------------
__global__ __launch_bounds__(256) void gates_pack_kernel(
    const float* __restrict__ q, const float* __restrict__ k,
    const float* __restrict__ v,
    const float* __restrict__ igk, const float* __restrict__ igb,
    const float* __restrict__ fgk, const float* __restrict__ fgb,
    float* __restrict__ ig_pre, float* __restrict__ lsf,
    char* __restrict__ kpack, char* __restrict__ vpack) {
  const int bid = blockIdx.x;
  if (bid < B_ * S_) {
    // ---- gates path (proven rounds 8-19) ----
    int bs = bid;
    int b = bs / S_, s = bs % S_;
    const float* qrow = q + ((size_t)b * S_ + s) * H_;
    const float* krow = k + ((size_t)b * S_ + s) * H_;
    const float* vrow = v + ((size_t)b * S_ + s) * H_;

    int h0 = threadIdx.x * 4;
    float4 q4 = *reinterpret_cast<const float4*>(qrow + h0);
    float4 k4 = *reinterpret_cast<const float4*>(krow + h0);
    float4 v4 = *reinterpret_cast<const float4*>(vrow + h0);
    float qv[4] = {q4.x, q4.y, q4.z, q4.w};
    float kv[4] = {k4.x, k4.y, k4.z, k4.w};
    float vv[4] = {v4.x, v4.y, v4.z, v4.w};

    const float4* igk4 = reinterpret_cast<const float4*>(igk);
    const float4* fgk4 = reinterpret_cast<const float4*>(fgk);

    float accI[NH_] = {0.f, 0.f, 0.f, 0.f};
    float accF[NH_] = {0.f, 0.f, 0.f, 0.f};
#pragma unroll
    for (int e = 0; e < 4; ++e) {
      int h = h0 + e;
      float4 wiq = igk4[h], wik = igk4[H_ + h], wiv = igk4[2 * H_ + h];
      float4 wfq = fgk4[h], wfk = fgk4[H_ + h], wfv = fgk4[2 * H_ + h];
      accI[0] += qv[e] * wiq.x + kv[e] * wik.x + vv[e] * wiv.x;
      accI[1] += qv[e] * wiq.y + kv[e] * wik.y + vv[e] * wiv.y;
      accI[2] += qv[e] * wiq.z + kv[e] * wik.z + vv[e] * wiv.z;
      accI[3] += qv[e] * wiq.w + kv[e] * wik.w + vv[e] * wiv.w;
      accF[0] += qv[e] * wfq.x + kv[e] * wfk.x + vv[e] * wfv.x;
      accF[1] += qv[e] * wfq.y + kv[e] * wfk.y + vv[e] * wfv.y;
      accF[2] += qv[e] * wfq.z + kv[e] * wfk.z + vv[e] * wfv.z;
      accF[3] += qv[e] * wfq.w + kv[e] * wfk.w + vv[e] * wfv.w;
    }
#pragma unroll
    for (int n = 0; n < NH_; ++n) {
      for (int m = 1; m < 64; m <<= 1) {
        accI[n] += __shfl_xor(accI[n], m);
        accF[n] += __shfl_xor(accF[n], m);
      }
    }
    __shared__ float red[4][8];
    int wave = threadIdx.x >> 6;
    int lane = threadIdx.x & 63;
    if (lane == 0) {
#pragma unroll
      for (int n = 0; n < NH_; ++n) {
        red[wave][n] = accI[n];
        red[wave][4 + n] = accF[n];
      }
    }
    __syncthreads();
    if (threadIdx.x < 8) {
      int t = threadIdx.x;
      float sum = red[0][t] + red[1][t] + red[2][t] + red[3][t];
      if (t < 4) {
        int n = t;
        ig_pre[((size_t)(b * NH_ + n)) * S_ + s] = sum + igb[n];
      } else {
        int n = t - 4;
        float x = sum + fgb[n];
        float ls = (x >= 0.f) ? -log1pf(expf(-x)) : (x - log1pf(expf(x)));
        lsf[((size_t)(b * NH_ + n)) * S_ + s] = ls;
      }
    }
    return;
  }

  // ---- pack path (proven rounds 11-19 layout) ----
  const int bidx = bid - B_ * S_;
  const int hd = bidx & 7, jt = bidx >> 3;
  const int b = hd >> 2, nh = hd & 3;
  const float* kgb = k + ((size_t)b * S_ + jt * 32) * H_ + nh * DH_;
  const float* vgb = v + ((size_t)b * S_ + jt * 32) * H_ + nh * DH_;
  char* kp = kpack + ((size_t)(hd * 64 + jt)) * KTILE_BYTES;
  char* vp = vpack + ((size_t)(hd * 64 + jt)) * VTILE_BYTES;
  const int tid = threadIdx.x;

  {
    int j = tid >> 3, sck = tid & 7;
    const float* row = kgb + (size_t)j * H_ + sck * 32;
    short8* out8 = reinterpret_cast<short8*>(kp) + j * 32;
#pragma unroll
    for (int u = 0; u < 4; ++u) {
      float4 a0 = *reinterpret_cast<const float4*>(row + 8 * u);
      float4 a1 = *reinterpret_cast<const float4*>(row + 8 * u + 4);
      out8[(4 * sck + u) ^ (j & 7)] = pack8(a0, a1);
    }
  }
  {
    int d = tid;
    int jsw = ((d >> 4) & 3) << 3;
    short4v* dst = reinterpret_cast<short4v*>(vp + (size_t)d * 72);
#pragma unroll
    for (int c = 0; c < 8; ++c) {
      short4v t;
#pragma unroll
      for (int e = 0; e < 4; ++e)
        t[e] = f2bf(vgb[(size_t)((4 * c + e) ^ jsw) * H_ + d]);
      dst[c] = t;
    }
    short4v z = {0, 0, 0, 0};
    dst[8] = z;
  }
}

// ---------------------------------------------------------------------------
// Kernel 2: per-(b,nh) scan — in-register (proven rounds 6-19).
// ---------------------------------------------------------------------------
__global__ __launch_bounds__(64) void scan_kernel(
    const float* __restrict__ ig_pre, const float* __restrict__ lsf,
    float* __restrict__ a_out, float* __restrict__ M_out,
    float* __restrict__ fl_out) {
  int hd = blockIdx.x;
  int lane = threadIdx.x;
  const float* ig = ig_pre + (size_t)hd * S_;
  const float* ls = lsf + (size_t)hd * S_;
  float xs[32], ys[32];
#pragma unroll
  for (int c = 0; c < 32; ++c) xs[c] = ls[c * 64 + lane];
#pragma unroll
  for (int c = 0; c < 32; ++c) ys[c] = ig[c * 64 + lane];

  float carry = 0.f;
  float mcarry = -INFINITY;
#pragma unroll
  for (int c = 0; c < 32; ++c) {
    int s = c * 64 + lane;
    float x = xs[c];
    for (int off = 1; off < 64; off <<= 1) {
      float t = __shfl_up(x, off);
      if (lane >= off) x += t;
    }
    float csum = carry + x;
    float a = ys[c] - csum;
    float y = a;
    for (int off = 1; off < 64; off <<= 1) {
      float t = __shfl_up(y, off);
      if (lane >= off) y = fmaxf(y, t);
    }
    float M = fmaxf(mcarry, y);
    a_out[(size_t)hd * S_ + s] = a;
    M_out[(size_t)hd * S_ + s] = M;
    fl_out[(size_t)hd * S_ + s] = expf(-(csum + M));
    carry = __shfl(csum, 63);
    mcarry = __shfl(M, 63);
  }
}

// ---------------------------------------------------------------------------
// Kernel 3: MFMA main — R17/R19 chassis (best measured) + T5 s_setprio.
// LDS: K0 16K | K1 16K | V0 18K | V1 18K = 69632 B; 2 blocks/CU.
// ---------------------------------------------------------------------------
#define KOFF0 0
#define KOFF1 16384
#define VOFF0 32768
#define VOFF1 51200
#define SMEM_BYTES 69632
#define VSTR 36

__global__ __launch_bounds__(256, 2) void mlstm_mfma(
    const float* __restrict__ q,
    const float* __restrict__ a_arr, const float* __restrict__ M_arr,
    const char* __restrict__ kpack, const char* __restrict__ vpack,
    short* __restrict__ po0, short* __restrict__ po1,
    short* __restrict__ po2, short* __restrict__ po3,
    float* __restrict__ rs0, float* __restrict__ rs1,
    float* __restrict__ rs2, float* __restrict__ rs3) {
  __shared__ __align__(16) char smem[SMEM_BYTES];

  const int bid = blockIdx.x;
  const int half = bid >> 8;
  const int idx = bid & 255;
  const int hd = idx & 7;
  const int u = idx >> 3;  // 0..31
  const int rt = half ? (u & 15) : (15 - (u & 15));
  const int p = half ? (2 + (u >> 4)) : (u >> 4);
  const int ntiles = rt + 1;

  const int b = hd >> 2, nh = hd & 3;
  const int i0 = rt * 128;

  const int tid = threadIdx.x;
  const int wave = tid >> 6;
  const int l = tid & 63;
  const int g = l >> 4;      // 0..3
  const int c16 = l & 15;    // 0..15
  const int iw0 = i0 + wave * 16;        // strip 0 rows
  const int iw1 = i0 + 64 + wave * 16;   // strip 1 rows

  const char* ktiles = kpack + (size_t)hd * 64 * KTILE_BYTES;
  const char* vtiles = vpack + (size_t)hd * 64 * VTILE_BYTES;

  // ---- Q fragments (B-operand), two strips ----
  short8 qf0[8], qf1[8];
  {
    const float* qp0 = q + ((size_t)b * S_ + (iw0 + c16)) * H_ + nh * DH_;
    const float* qp1 = q + ((size_t)b * S_ + (iw1 + c16)) * H_ + nh * DH_;
#pragma unroll
    for (int c = 0; c < 8; ++c) {
      int d0 = c * 32 + g * 8;
      qf0[c] = pack8(*reinterpret_cast<const float4*>(qp0 + d0),
                     *reinterpret_cast<const float4*>(qp0 + d0 + 4));
      qf1[c] = pack8(*reinterpret_cast<const float4*>(qp1 + d0),
                     *reinterpret_cast<const float4*>(qp1 + d0 + 4));
    }
  }
  const float Mrs0 = M_arr[(size_t)hd * S_ + iw0 + c16];
  const float Mrs1 = M_arr[(size_t)hd * S_ + iw1 + c16];
  const int i_row0 = iw0 + c16;
  const int i_row1 = iw1 + c16;

  f32x4 oa0[16], oa1[16];
#pragma unroll
  for (int d = 0; d < 16; ++d) {
    oa0[d] = (f32x4){0.f, 0.f, 0.f, 0.f};
    oa1[d] = (f32x4){0.f, 0.f, 0.f, 0.f};
  }
  float rss0 = 0.f, rss1 = 0.f;

  const float* agb = a_arr + (size_t)hd * S_;

  auto stage = [&](int jt, int buf) {
    const char* kt = ktiles + (size_t)jt * KTILE_BYTES + wave * 4096;
    char* kl = smem + (buf ? KOFF1 : KOFF0) + wave * 4096;
#pragma unroll
    for (int uu = 0; uu < 4; ++uu)
      gload16(kt + uu * 1024 + l * 16, kl + uu * 1024);
    const char* vt = vtiles + (size_t)jt * VTILE_BYTES + wave * 4608;
    char* vl = smem + (buf ? VOFF1 : VOFF0) + wave * 4608;
#pragma unroll
    for (int uu = 0; uu < 4; ++uu)
      gload16(vt + uu * 1024 + l * 16, vl + uu * 1024);
#pragma unroll
    for (int uu = 0; uu < 2; ++uu)
      gload4(vt + 4096 + uu * 256 + l * 4, vl + 4096 + uu * 256);
  };

  stage(p, 0);
  __syncthreads();

  for (int n = 0; n < ntiles; ++n) {
    const int jt = p + 4 * n;
    const int cur = n & 1;
    if (n + 1 < ntiles) stage(jt + 4, cur ^ 1);  // DMA in flight over compute

    {
      const int j0 = jt * 32;
      const short8* kb8 =
          reinterpret_cast<const short8*>(smem + (cur ? KOFF1 : KOFF0));
      const short* vt =
          reinterpret_cast<const short*>(smem + (cur ? VOFF1 : VOFF0));
      // ---- S^T = K Q (swapped), both strips; kf loaded once ----
      f32x4 sa0 = {0.f, 0.f, 0.f, 0.f}, sa1 = {0.f, 0.f, 0.f, 0.f};
      f32x4 sb0 = {0.f, 0.f, 0.f, 0.f}, sb1 = {0.f, 0.f, 0.f, 0.f};
      __builtin_amdgcn_s_setprio(1);
#pragma unroll
      for (int c = 0; c < 8; ++c) {
        int row0 = c16, row1 = 16 + c16;
        int slot = 4 * c + g;
        short8 kf0 = kb8[row0 * 32 + (slot ^ (row0 & 7))];
        short8 kf1 = kb8[row1 * 32 + (slot ^ (row1 & 7))];
        sa0 = __builtin_amdgcn_mfma_f32_16x16x32_bf16(kf0, qf0[c], sa0, 0, 0, 0);
        sa1 = __builtin_amdgcn_mfma_f32_16x16x32_bf16(kf1, qf0[c], sa1, 0, 0, 0);
        sb0 = __builtin_amdgcn_mfma_f32_16x16x32_bf16(kf0, qf1[c], sb0, 0, 0, 0);
        sb1 = __builtin_amdgcn_mfma_f32_16x16x32_bf16(kf1, qf1[c], sb1, 0, 0, 0);
      }
      __builtin_amdgcn_s_setprio(0);
      // ---- weights, causal mask, rowsums (per-lane) ----
      float4 av0 = *reinterpret_cast<const float4*>(agb + j0 + 4 * g);
      float4 av1 = *reinterpret_cast<const float4*>(agb + j0 + 16 + 4 * g);
      float w00[4], w01[4], w10[4], w11[4];
#pragma unroll
      for (int r = 0; r < 4; ++r) {
        float aa0 = reinterpret_cast<const float*>(&av0)[r];
        float aa1 = reinterpret_cast<const float*>(&av1)[r];
        int j_0 = j0 + 4 * g + r, j_1 = j0 + 16 + 4 * g + r;
        float e00 = __expf(aa0 - Mrs0), e01 = __expf(aa1 - Mrs0);
        float e10 = __expf(aa0 - Mrs1), e11 = __expf(aa1 - Mrs1);
        float t;
        t = sa0[r] * 0.0625f * e00; w00[r] = (j_0 <= i_row0) ? t : 0.f;
        t = sa1[r] * 0.0625f * e01; w01[r] = (j_1 <= i_row0) ? t : 0.f;
        t = sb0[r] * 0.0625f * e10; w10[r] = (j_0 <= i_row1) ? t : 0.f;
        t = sb1[r] * 0.0625f * e11; w11[r] = (j_1 <= i_row1) ? t : 0.f;
        rss0 += w00[r] + w01[r];
        rss1 += w10[r] + w11[r];
      }
      // ---- P -> bf16 pairs in-register, both strips ----
      unsigned pA0, pB0, pC0, pD0, pA1, pB1, pC1, pD1;
      asm("v_cvt_pk_bf16_f32 %0, %1, %2" : "=v"(pA0) : "v"(w00[0]), "v"(w00[1]));
      asm("v_cvt_pk_bf16_f32 %0, %1, %2" : "=v"(pB0) : "v"(w00[2]), "v"(w00[3]));
      asm("v_cvt_pk_bf16_f32 %0, %1, %2" : "=v"(pC0) : "v"(w01[0]), "v"(w01[1]));
      asm("v_cvt_pk_bf16_f32 %0, %1, %2" : "=v"(pD0) : "v"(w01[2]), "v"(w01[3]));
      asm("v_cvt_pk_bf16_f32 %0, %1, %2" : "=v"(pA1) : "v"(w10[0]), "v"(w10[1]));
      asm("v_cvt_pk_bf16_f32 %0, %1, %2" : "=v"(pB1) : "v"(w10[2]), "v"(w10[3]));
      asm("v_cvt_pk_bf16_f32 %0, %1, %2" : "=v"(pC1) : "v"(w11[0]), "v"(w11[1]));
      asm("v_cvt_pk_bf16_f32 %0, %1, %2" : "=v"(pD1) : "v"(w11[2]), "v"(w11[3]));
      // ---- gather PV A-frags: P[i=c16][j=8g..8g+7] per strip ----
      int src0 = 32 * (g & 1) + c16;
      int src1 = src0 + 16;
      bool lo = (g < 2);
      union { int u[4]; short8 s; } pu0, pu1;
      {
        int a0s = __shfl((int)pA0, src0, 64), b0s = __shfl((int)pB0, src0, 64);
        int c0s = __shfl((int)pC0, src0, 64), d0s = __shfl((int)pD0, src0, 64);
        int a1s = __shfl((int)pA0, src1, 64), b1s = __shfl((int)pB0, src1, 64);
        int c1s = __shfl((int)pC0, src1, 64), d1s = __shfl((int)pD0, src1, 64);
        pu0.u[0] = lo ? a0s : c0s;
        pu0.u[1] = lo ? b0s : d0s;
        pu0.u[2] = lo ? a1s : c1s;
        pu0.u[3] = lo ? b1s : d1s;
      }
      {
        int a0s = __shfl((int)pA1, src0, 64), b0s = __shfl((int)pB1, src0, 64);
        int c0s = __shfl((int)pC1, src0, 64), d0s = __shfl((int)pD1, src0, 64);
        int a1s = __shfl((int)pA1, src1, 64), b1s = __shfl((int)pB1, src1, 64);
        int c1s = __shfl((int)pC1, src1, 64), d1s = __shfl((int)pD1, src1, 64);
        pu1.u[0] = lo ? a0s : c0s;
        pu1.u[1] = lo ? b0s : d0s;
        pu1.u[2] = lo ? a1s : c1s;
        pu1.u[3] = lo ? b1s : d1s;
      }
      short8 pa0 = pu0.s, pa1 = pu1.s;
      // ---- O += P V; vf loaded once, used by both strips ----
      __builtin_amdgcn_s_setprio(1);
#pragma unroll
      for (int dq = 0; dq < 16; ++dq) {
        short8 vf = *reinterpret_cast<const short8*>(
            vt + (16 * dq + c16) * VSTR + 8 * (g ^ (dq & 3)));
        oa0[dq] = __builtin_amdgcn_mfma_f32_16x16x32_bf16(pa0, vf, oa0[dq], 0, 0, 0);
        oa1[dq] = __builtin_amdgcn_mfma_f32_16x16x32_bf16(pa1, vf, oa1[dq], 0, 0, 0);
      }
      __builtin_amdgcn_s_setprio(0);
    }
    __syncthreads();  // drains vmcnt (next tile landed) + all LDS reads done
  }

  // ---- rowsum reduce across g-groups (same c16) ----
  rss0 += __shfl_xor(rss0, 16);
  rss0 += __shfl_xor(rss0, 32);
  rss1 += __shfl_xor(rss1, 16);
  rss1 += __shfl_xor(rss1, 32);

  float* rsP = (p == 0) ? rs0 : (p == 1) ? rs1 : (p == 2) ? rs2 : rs3;
  if (l < 16) {
    rsP[hd * S_ + iw0 + l] = rss0;
    rsP[hd * S_ + iw1 + l] = rss1;
  }

  short* po = (p == 0) ? po0 : (p == 1) ? po1 : (p == 2) ? po2 : po3;
#pragma unroll
  for (int dq = 0; dq < 16; ++dq)
#pragma unroll
    for (int r = 0; r < 4; ++r) {
      po[((size_t)(hd * S_ + iw0 + 4 * g + r)) * DH_ + dq * 16 + c16] =
          f2bf(oa0[dq][r]);
      po[((size_t)(hd * S_ + iw1 + 4 * g + r)) * DH_ + dq * 16 + c16] =
          f2bf(oa1[dq][r]);
    }
}

// ---------------------------------------------------------------------------
// Kernel 4: combine 4 bf16 partials -> normalizer + layernorm -> out (f32).
// ---------------------------------------------------------------------------
__global__ __launch_bounds__(256) void combine_kernel(
    const short* __restrict__ po0, const short* __restrict__ po1,
    const short* __restrict__ po2, const short* __restrict__ po3,
    const float* __restrict__ rs0, const float* __restrict__ rs1,
    const float* __restrict__ rs2, const float* __restrict__ rs3,
    const float* __restrict__ fl_arr, const float* __restrict__ scale,
    float* __restrict__ out) {
  int ridx = blockIdx.x * 4 + (threadIdx.x >> 6);
  int lane = threadIdx.x & 63;
  int hd = ridx >> 11, i = ridx & 2047;
  int b = hd >> 2, nh = hd & 3;

  size_t poi = ((size_t)(hd * S_ + i)) * DH_ + lane * 4;
  short4v a4 = *reinterpret_cast<const short4v*>(po0 + poi);
  short4v b4 = *reinterpret_cast<const short4v*>(po1 + poi);
  short4v c4 = *reinterpret_cast<const short4v*>(po2 + poi);
  short4v d4 = *reinterpret_cast<const short4v*>(po3 + poi);

  float rsum = rs0[hd * S_ + i] + rs1[hd * S_ + i] + rs2[hd * S_ + i] +
               rs3[hd * S_ + i];
  float o0 = bf2f(a4[0]) + bf2f(b4[0]) + bf2f(c4[0]) + bf2f(d4[0]);
  float o1 = bf2f(a4[1]) + bf2f(b4[1]) + bf2f(c4[1]) + bf2f(d4[1]);
  float o2 = bf2f(a4[2]) + bf2f(b4[2]) + bf2f(c4[2]) + bf2f(d4[2]);
  float o3 = bf2f(a4[3]) + bf2f(b4[3]) + bf2f(c4[3]) + bf2f(d4[3]);

  float fl = fl_arr[(size_t)hd * S_ + i];
  float inv = 1.f / (fmaxf(fabsf(rsum), fl) + 1e-6f);
  o0 *= inv; o1 *= inv; o2 *= inv; o3 *= inv;

  float s1 = o0 + o1 + o2 + o3;
  float s2 = o0 * o0 + o1 * o1 + o2 * o2 + o3 * o3;
#pragma unroll
  for (int m = 1; m < 64; m <<= 1) {
    s1 += __shfl_xor(s1, m);
    s2 += __shfl_xor(s2, m);
  }
  float mean = s1 * (1.f / DH_);
  float var = s2 * (1.f / DH_) - mean * mean;
  float rstd = rsqrtf(var + 1e-6f);

  const float* scp = scale + nh * DH_ + lane * 4;
  float4 res;
  res.x = (o0 - mean) * rstd * scp[0];
  res.y = (o1 - mean) * rstd * scp[1];
  res.z = (o2 - mean) * rstd * scp[2];
  res.w = (o3 - mean) * rstd * scp[3];
  float* op = out + ((size_t)b * S_ + i) * H_ + nh * DH_ + lane * 4;
  *reinterpret_cast<float4*>(op) = res;
}

// ---------------------------------------------------------------------------
extern "C" void kernel_launch(void* const* d_in, const int* in_sizes, int n_in,
                              void* d_out, int out_size, void* d_ws,
                              size_t ws_size, hipStream_t stream) {
  const float* q   = (const float*)d_in[0];
  const float* k   = (const float*)d_in[1];
  const float* v   = (const float*)d_in[2];
  const float* igk = (const float*)d_in[3];
  const float* igb = (const float*)d_in[4];
  const float* fgk = (const float*)d_in[5];
  const float* fgb = (const float*)d_in[6];
  const float* scl = (const float*)d_in[7];
  float* out = (float*)d_out;

  const size_t seq = (size_t)B_ * NH_ * S_;  // 16384
  const size_t pon = (size_t)8 * 2048 * 256; // elements per partial buffer
  float* ws = (float*)d_ws;
  float* ig_pre = ws;
  float* lsf    = ws + seq;
  float* a_arr  = ws + 2 * seq;
  float* M_arr  = ws + 3 * seq;
  float* fl_arr = ws + 4 * seq;
  float* rs0    = ws + 5 * seq;
  float* rs1    = ws + 6 * seq;
  float* rs2    = ws + 7 * seq;
  float* rs3    = ws + 8 * seq;
  char*  kpack  = (char*)(ws + 9 * seq);                 // 8 MB
  char*  vpack  = kpack + (size_t)8 * 64 * KTILE_BYTES;  // 9.4 MB
  short* po0    = (short*)(vpack + (size_t)8 * 64 * VTILE_BYTES);
  short* po1    = po0 + pon;
  short* po2    = po1 + pon;
  short* po3    = po2 + pon;   // bf16 partials: 4 x 8.4 MB; total ~52 MB

  gates_pack_kernel<<<B_ * S_ + 512, 256, 0, stream>>>(
      q, k, v, igk, igb, fgk, fgb, ig_pre, lsf, kpack, vpack);
  scan_kernel<<<B_ * NH_, 64, 0, stream>>>(ig_pre, lsf, a_arr, M_arr, fl_arr);
  mlstm_mfma<<<512, 256, 0, stream>>>(q, a_arr, M_arr, kpack, vpack,
                                      po0, po1, po2, po3,
                                      rs0, rs1, rs2, rs3);
  combine_kernel<<<B_ * NH_ * S_ / 4, 256, 0, stream>>>(
      po0, po1, po2, po3, rs0, rs1, rs2, rs3, fl_arr, scl, out);
}

// Round 22
// 154.543 us; speedup vs baseline: 1.0649x; 1.0649x over previous
//
#include <hip/hip_runtime.h>
#include <hip/hip_bf16.h>
#include <math.h>

#define B_  2
#define S_  2048
#define H_  1024
#define NH_ 4
#define DH_ 256

typedef __attribute__((ext_vector_type(8))) short short8;
typedef __attribute__((ext_vector_type(4))) short short4v;
typedef __attribute__((ext_vector_type(4))) float f32x4;

#define KTILE_BYTES 16384   // 32 j x 256 d x 2B (swizzled slots)
#define VTILE_BYTES 18432   // 256 d x 36 shorts (transposed, swizzled, padded)

static __device__ __forceinline__ short f2bf(float x) {
  __hip_bfloat16 h = __float2bfloat16(x);
  union { __hip_bfloat16 h; short s; } u;
  u.h = h;
  return u.s;
}

static __device__ __forceinline__ float bf2f(short s) {
  union { unsigned u; float f; } t;
  t.u = ((unsigned)(unsigned short)s) << 16;
  return t.f;
}

static __device__ __forceinline__ short8 pack8(const float4& a, const float4& b) {
  short8 t;
  t[0] = f2bf(a.x); t[1] = f2bf(a.y); t[2] = f2bf(a.z); t[3] = f2bf(a.w);
  t[4] = f2bf(b.x); t[5] = f2bf(b.y); t[6] = f2bf(b.z); t[7] = f2bf(b.w);
  return t;
}

static __device__ __forceinline__ void gload16(const void* g, void* l) {
  __builtin_amdgcn_global_load_lds(
      (const __attribute__((address_space(1))) unsigned int*)g,
      (__attribute__((address_space(3))) unsigned int*)l, 16, 0, 0);
}
static __device__ __forceinline__ void gload4(const void* g, void* l) {
  __builtin_amdgcn_global_load_lds(
      (const __attribute__((address_space(1))) unsigned int*)g,
      (__attribute__((address_space(3))) unsigned int*)l, 4, 0, 0);
}

// ---------------------------------------------------------------------------
// Kernel 1: FUSED gates (blocks 0..4095 = B_*S_) + pack K/V (4096..4607).
// (R20 lesson: gates needs B_*S_=4096 blocks — b = bid/S_.)
// ---------------------------------------------------------------------------
__global__ __launch_bounds__(256) void gates_pack_kernel(
    const float* __restrict__ q, const float* __restrict__ k,
    const float* __restrict__ v,
    const float* __restrict__ igk, const float* __restrict__ igb,
    const float* __restrict__ fgk, const float* __restrict__ fgb,
    float* __restrict__ ig_pre, float* __restrict__ lsf,
    char* __restrict__ kpack, char* __restrict__ vpack) {
  const int bid = blockIdx.x;
  if (bid < B_ * S_) {
    // ---- gates path (proven rounds 8-21) ----
    int bs = bid;
    int b = bs / S_, s = bs % S_;
    const float* qrow = q + ((size_t)b * S_ + s) * H_;
    const float* krow = k + ((size_t)b * S_ + s) * H_;
    const float* vrow = v + ((size_t)b * S_ + s) * H_;

    int h0 = threadIdx.x * 4;
    float4 q4 = *reinterpret_cast<const float4*>(qrow + h0);
    float4 k4 = *reinterpret_cast<const float4*>(krow + h0);
    float4 v4 = *reinterpret_cast<const float4*>(vrow + h0);
    float qv[4] = {q4.x, q4.y, q4.z, q4.w};
    float kv[4] = {k4.x, k4.y, k4.z, k4.w};
    float vv[4] = {v4.x, v4.y, v4.z, v4.w};

    const float4* igk4 = reinterpret_cast<const float4*>(igk);
    const float4* fgk4 = reinterpret_cast<const float4*>(fgk);

    float accI[NH_] = {0.f, 0.f, 0.f, 0.f};
    float accF[NH_] = {0.f, 0.f, 0.f, 0.f};
#pragma unroll
    for (int e = 0; e < 4; ++e) {
      int h = h0 + e;
      float4 wiq = igk4[h], wik = igk4[H_ + h], wiv = igk4[2 * H_ + h];
      float4 wfq = fgk4[h], wfk = fgk4[H_ + h], wfv = fgk4[2 * H_ + h];
      accI[0] += qv[e] * wiq.x + kv[e] * wik.x + vv[e] * wiv.x;
      accI[1] += qv[e] * wiq.y + kv[e] * wik.y + vv[e] * wiv.y;
      accI[2] += qv[e] * wiq.z + kv[e] * wik.z + vv[e] * wiv.z;
      accI[3] += qv[e] * wiq.w + kv[e] * wik.w + vv[e] * wiv.w;
      accF[0] += qv[e] * wfq.x + kv[e] * wfk.x + vv[e] * wfv.x;
      accF[1] += qv[e] * wfq.y + kv[e] * wfk.y + vv[e] * wfv.y;
      accF[2] += qv[e] * wfq.z + kv[e] * wfk.z + vv[e] * wfv.z;
      accF[3] += qv[e] * wfq.w + kv[e] * wfk.w + vv[e] * wfv.w;
    }
#pragma unroll
    for (int n = 0; n < NH_; ++n) {
      for (int m = 1; m < 64; m <<= 1) {
        accI[n] += __shfl_xor(accI[n], m);
        accF[n] += __shfl_xor(accF[n], m);
      }
    }
    __shared__ float red[4][8];
    int wave = threadIdx.x >> 6;
    int lane = threadIdx.x & 63;
    if (lane == 0) {
#pragma unroll
      for (int n = 0; n < NH_; ++n) {
        red[wave][n] = accI[n];
        red[wave][4 + n] = accF[n];
      }
    }
    __syncthreads();
    if (threadIdx.x < 8) {
      int t = threadIdx.x;
      float sum = red[0][t] + red[1][t] + red[2][t] + red[3][t];
      if (t < 4) {
        int n = t;
        ig_pre[((size_t)(b * NH_ + n)) * S_ + s] = sum + igb[n];
      } else {
        int n = t - 4;
        float x = sum + fgb[n];
        float ls = (x >= 0.f) ? -log1pf(expf(-x)) : (x - log1pf(expf(x)));
        lsf[((size_t)(b * NH_ + n)) * S_ + s] = ls;
      }
    }
    return;
  }

  // ---- pack path (proven rounds 11-21 layout) ----
  const int bidx = bid - B_ * S_;
  const int hd = bidx & 7, jt = bidx >> 3;
  const int b = hd >> 2, nh = hd & 3;
  const float* kgb = k + ((size_t)b * S_ + jt * 32) * H_ + nh * DH_;
  const float* vgb = v + ((size_t)b * S_ + jt * 32) * H_ + nh * DH_;
  char* kp = kpack + ((size_t)(hd * 64 + jt)) * KTILE_BYTES;
  char* vp = vpack + ((size_t)(hd * 64 + jt)) * VTILE_BYTES;
  const int tid = threadIdx.x;

  {
    int j = tid >> 3, sck = tid & 7;
    const float* row = kgb + (size_t)j * H_ + sck * 32;
    short8* out8 = reinterpret_cast<short8*>(kp) + j * 32;
#pragma unroll
    for (int u = 0; u < 4; ++u) {
      float4 a0 = *reinterpret_cast<const float4*>(row + 8 * u);
      float4 a1 = *reinterpret_cast<const float4*>(row + 8 * u + 4);
      out8[(4 * sck + u) ^ (j & 7)] = pack8(a0, a1);
    }
  }
  {
    int d = tid;
    int jsw = ((d >> 4) & 3) << 3;
    short4v* dst = reinterpret_cast<short4v*>(vp + (size_t)d * 72);
#pragma unroll
    for (int c = 0; c < 8; ++c) {
      short4v t;
#pragma unroll
      for (int e = 0; e < 4; ++e)
        t[e] = f2bf(vgb[(size_t)((4 * c + e) ^ jsw) * H_ + d]);
      dst[c] = t;
    }
    short4v z = {0, 0, 0, 0};
    dst[8] = z;
  }
}

// ---------------------------------------------------------------------------
// Kernel 2: per-(b,nh) scan — in-register (proven rounds 6-21).
// ---------------------------------------------------------------------------
__global__ __launch_bounds__(64) void scan_kernel(
    const float* __restrict__ ig_pre, const float* __restrict__ lsf,
    float* __restrict__ a_out, float* __restrict__ M_out,
    float* __restrict__ fl_out) {
  int hd = blockIdx.x;
  int lane = threadIdx.x;
  const float* ig = ig_pre + (size_t)hd * S_;
  const float* ls = lsf + (size_t)hd * S_;
  float xs[32], ys[32];
#pragma unroll
  for (int c = 0; c < 32; ++c) xs[c] = ls[c * 64 + lane];
#pragma unroll
  for (int c = 0; c < 32; ++c) ys[c] = ig[c * 64 + lane];

  float carry = 0.f;
  float mcarry = -INFINITY;
#pragma unroll
  for (int c = 0; c < 32; ++c) {
    int s = c * 64 + lane;
    float x = xs[c];
    for (int off = 1; off < 64; off <<= 1) {
      float t = __shfl_up(x, off);
      if (lane >= off) x += t;
    }
    float csum = carry + x;
    float a = ys[c] - csum;
    float y = a;
    for (int off = 1; off < 64; off <<= 1) {
      float t = __shfl_up(y, off);
      if (lane >= off) y = fmaxf(y, t);
    }
    float M = fmaxf(mcarry, y);
    a_out[(size_t)hd * S_ + s] = a;
    M_out[(size_t)hd * S_ + s] = M;
    fl_out[(size_t)hd * S_ + s] = expf(-(csum + M));
    carry = __shfl(csum, 63);
    mcarry = __shfl(M, 63);
  }
}

// ---------------------------------------------------------------------------
// Kernel 3: MFMA main — R17/R19 chassis, NO setprio (R21 A/B: setprio cost
// 12% — both co-resident blocks are lockstep, so boosting MFMA starved the
// partner's staging DMA). 128-row blocks, 4 waves, 2 strips/wave, DMA
// staging, 4-way parity split, bf16 partial stores.
// LDS: K0 16K | K1 16K | V0 18K | V1 18K = 69632 B; 2 blocks/CU.
// ---------------------------------------------------------------------------
#define KOFF0 0
#define KOFF1 16384
#define VOFF0 32768
#define VOFF1 51200
#define SMEM_BYTES 69632
#define VSTR 36

__global__ __launch_bounds__(256, 2) void mlstm_mfma(
    const float* __restrict__ q,
    const float* __restrict__ a_arr, const float* __restrict__ M_arr,
    const char* __restrict__ kpack, const char* __restrict__ vpack,
    short* __restrict__ po0, short* __restrict__ po1,
    short* __restrict__ po2, short* __restrict__ po3,
    float* __restrict__ rs0, float* __restrict__ rs1,
    float* __restrict__ rs2, float* __restrict__ rs3) {
  __shared__ __align__(16) char smem[SMEM_BYTES];

  const int bid = blockIdx.x;
  const int half = bid >> 8;
  const int idx = bid & 255;
  const int hd = idx & 7;
  const int u = idx >> 3;  // 0..31
  const int rt = half ? (u & 15) : (15 - (u & 15));
  const int p = half ? (2 + (u >> 4)) : (u >> 4);
  const int ntiles = rt + 1;

  const int b = hd >> 2, nh = hd & 3;
  const int i0 = rt * 128;

  const int tid = threadIdx.x;
  const int wave = tid >> 6;
  const int l = tid & 63;
  const int g = l >> 4;      // 0..3
  const int c16 = l & 15;    // 0..15
  const int iw0 = i0 + wave * 16;        // strip 0 rows
  const int iw1 = i0 + 64 + wave * 16;   // strip 1 rows

  const char* ktiles = kpack + (size_t)hd * 64 * KTILE_BYTES;
  const char* vtiles = vpack + (size_t)hd * 64 * VTILE_BYTES;

  // ---- Q fragments (B-operand), two strips ----
  short8 qf0[8], qf1[8];
  {
    const float* qp0 = q + ((size_t)b * S_ + (iw0 + c16)) * H_ + nh * DH_;
    const float* qp1 = q + ((size_t)b * S_ + (iw1 + c16)) * H_ + nh * DH_;
#pragma unroll
    for (int c = 0; c < 8; ++c) {
      int d0 = c * 32 + g * 8;
      qf0[c] = pack8(*reinterpret_cast<const float4*>(qp0 + d0),
                     *reinterpret_cast<const float4*>(qp0 + d0 + 4));
      qf1[c] = pack8(*reinterpret_cast<const float4*>(qp1 + d0),
                     *reinterpret_cast<const float4*>(qp1 + d0 + 4));
    }
  }
  const float Mrs0 = M_arr[(size_t)hd * S_ + iw0 + c16];
  const float Mrs1 = M_arr[(size_t)hd * S_ + iw1 + c16];
  const int i_row0 = iw0 + c16;
  const int i_row1 = iw1 + c16;

  f32x4 oa0[16], oa1[16];
#pragma unroll
  for (int d = 0; d < 16; ++d) {
    oa0[d] = (f32x4){0.f, 0.f, 0.f, 0.f};
    oa1[d] = (f32x4){0.f, 0.f, 0.f, 0.f};
  }
  float rss0 = 0.f, rss1 = 0.f;

  const float* agb = a_arr + (size_t)hd * S_;

  auto stage = [&](int jt, int buf) {
    const char* kt = ktiles + (size_t)jt * KTILE_BYTES + wave * 4096;
    char* kl = smem + (buf ? KOFF1 : KOFF0) + wave * 4096;
#pragma unroll
    for (int uu = 0; uu < 4; ++uu)
      gload16(kt + uu * 1024 + l * 16, kl + uu * 1024);
    const char* vt = vtiles + (size_t)jt * VTILE_BYTES + wave * 4608;
    char* vl = smem + (buf ? VOFF1 : VOFF0) + wave * 4608;
#pragma unroll
    for (int uu = 0; uu < 4; ++uu)
      gload16(vt + uu * 1024 + l * 16, vl + uu * 1024);
#pragma unroll
    for (int uu = 0; uu < 2; ++uu)
      gload4(vt + 4096 + uu * 256 + l * 4, vl + 4096 + uu * 256);
  };

  stage(p, 0);
  __syncthreads();

  for (int n = 0; n < ntiles; ++n) {
    const int jt = p + 4 * n;
    const int cur = n & 1;
    if (n + 1 < ntiles) stage(jt + 4, cur ^ 1);  // DMA in flight over compute

    {
      const int j0 = jt * 32;
      const short8* kb8 =
          reinterpret_cast<const short8*>(smem + (cur ? KOFF1 : KOFF0));
      const short* vt =
          reinterpret_cast<const short*>(smem + (cur ? VOFF1 : VOFF0));
      // ---- S^T = K Q (swapped), both strips; kf loaded once ----
      f32x4 sa0 = {0.f, 0.f, 0.f, 0.f}, sa1 = {0.f, 0.f, 0.f, 0.f};
      f32x4 sb0 = {0.f, 0.f, 0.f, 0.f}, sb1 = {0.f, 0.f, 0.f, 0.f};
#pragma unroll
      for (int c = 0; c < 8; ++c) {
        int row0 = c16, row1 = 16 + c16;
        int slot = 4 * c + g;
        short8 kf0 = kb8[row0 * 32 + (slot ^ (row0 & 7))];
        short8 kf1 = kb8[row1 * 32 + (slot ^ (row1 & 7))];
        sa0 = __builtin_amdgcn_mfma_f32_16x16x32_bf16(kf0, qf0[c], sa0, 0, 0, 0);
        sa1 = __builtin_amdgcn_mfma_f32_16x16x32_bf16(kf1, qf0[c], sa1, 0, 0, 0);
        sb0 = __builtin_amdgcn_mfma_f32_16x16x32_bf16(kf0, qf1[c], sb0, 0, 0, 0);
        sb1 = __builtin_amdgcn_mfma_f32_16x16x32_bf16(kf1, qf1[c], sb1, 0, 0, 0);
      }
      // ---- weights, causal mask, rowsums (per-lane) ----
      float4 av0 = *reinterpret_cast<const float4*>(agb + j0 + 4 * g);
      float4 av1 = *reinterpret_cast<const float4*>(agb + j0 + 16 + 4 * g);
      float w00[4], w01[4], w10[4], w11[4];
#pragma unroll
      for (int r = 0; r < 4; ++r) {
        float aa0 = reinterpret_cast<const float*>(&av0)[r];
        float aa1 = reinterpret_cast<const float*>(&av1)[r];
        int j_0 = j0 + 4 * g + r, j_1 = j0 + 16 + 4 * g + r;
        float e00 = __expf(aa0 - Mrs0), e01 = __expf(aa1 - Mrs0);
        float e10 = __expf(aa0 - Mrs1), e11 = __expf(aa1 - Mrs1);
        float t;
        t = sa0[r] * 0.0625f * e00; w00[r] = (j_0 <= i_row0) ? t : 0.f;
        t = sa1[r] * 0.0625f * e01; w01[r] = (j_1 <= i_row0) ? t : 0.f;
        t = sb0[r] * 0.0625f * e10; w10[r] = (j_0 <= i_row1) ? t : 0.f;
        t = sb1[r] * 0.0625f * e11; w11[r] = (j_1 <= i_row1) ? t : 0.f;
        rss0 += w00[r] + w01[r];
        rss1 += w10[r] + w11[r];
      }
      // ---- P -> bf16 pairs in-register, both strips ----
      unsigned pA0, pB0, pC0, pD0, pA1, pB1, pC1, pD1;
      asm("v_cvt_pk_bf16_f32 %0, %1, %2" : "=v"(pA0) : "v"(w00[0]), "v"(w00[1]));
      asm("v_cvt_pk_bf16_f32 %0, %1, %2" : "=v"(pB0) : "v"(w00[2]), "v"(w00[3]));
      asm("v_cvt_pk_bf16_f32 %0, %1, %2" : "=v"(pC0) : "v"(w01[0]), "v"(w01[1]));
      asm("v_cvt_pk_bf16_f32 %0, %1, %2" : "=v"(pD0) : "v"(w01[2]), "v"(w01[3]));
      asm("v_cvt_pk_bf16_f32 %0, %1, %2" : "=v"(pA1) : "v"(w10[0]), "v"(w10[1]));
      asm("v_cvt_pk_bf16_f32 %0, %1, %2" : "=v"(pB1) : "v"(w10[2]), "v"(w10[3]));
      asm("v_cvt_pk_bf16_f32 %0, %1, %2" : "=v"(pC1) : "v"(w11[0]), "v"(w11[1]));
      asm("v_cvt_pk_bf16_f32 %0, %1, %2" : "=v"(pD1) : "v"(w11[2]), "v"(w11[3]));
      // ---- gather PV A-frags: P[i=c16][j=8g..8g+7] per strip ----
      int src0 = 32 * (g & 1) + c16;
      int src1 = src0 + 16;
      bool lo = (g < 2);
      union { int u[4]; short8 s; } pu0, pu1;
      {
        int a0s = __shfl((int)pA0, src0, 64), b0s = __shfl((int)pB0, src0, 64);
        int c0s = __shfl((int)pC0, src0, 64), d0s = __shfl((int)pD0, src0, 64);
        int a1s = __shfl((int)pA0, src1, 64), b1s = __shfl((int)pB0, src1, 64);
        int c1s = __shfl((int)pC0, src1, 64), d1s = __shfl((int)pD0, src1, 64);
        pu0.u[0] = lo ? a0s : c0s;
        pu0.u[1] = lo ? b0s : d0s;
        pu0.u[2] = lo ? a1s : c1s;
        pu0.u[3] = lo ? b1s : d1s;
      }
      {
        int a0s = __shfl((int)pA1, src0, 64), b0s = __shfl((int)pB1, src0, 64);
        int c0s = __shfl((int)pC1, src0, 64), d0s = __shfl((int)pD1, src0, 64);
        int a1s = __shfl((int)pA1, src1, 64), b1s = __shfl((int)pB1, src1, 64);
        int c1s = __shfl((int)pC1, src1, 64), d1s = __shfl((int)pD1, src1, 64);
        pu1.u[0] = lo ? a0s : c0s;
        pu1.u[1] = lo ? b0s : d0s;
        pu1.u[2] = lo ? a1s : c1s;
        pu1.u[3] = lo ? b1s : d1s;
      }
      short8 pa0 = pu0.s, pa1 = pu1.s;
      // ---- O += P V; vf loaded once, used by both strips ----
#pragma unroll
      for (int dq = 0; dq < 16; ++dq) {
        short8 vf = *reinterpret_cast<const short8*>(
            vt + (16 * dq + c16) * VSTR + 8 * (g ^ (dq & 3)));
        oa0[dq] = __builtin_amdgcn_mfma_f32_16x16x32_bf16(pa0, vf, oa0[dq], 0, 0, 0);
        oa1[dq] = __builtin_amdgcn_mfma_f32_16x16x32_bf16(pa1, vf, oa1[dq], 0, 0, 0);
      }
    }
    __syncthreads();  // drains vmcnt (next tile landed) + all LDS reads done
  }

  // ---- rowsum reduce across g-groups (same c16) ----
  rss0 += __shfl_xor(rss0, 16);
  rss0 += __shfl_xor(rss0, 32);
  rss1 += __shfl_xor(rss1, 16);
  rss1 += __shfl_xor(rss1, 32);

  float* rsP = (p == 0) ? rs0 : (p == 1) ? rs1 : (p == 2) ? rs2 : rs3;
  if (l < 16) {
    rsP[hd * S_ + iw0 + l] = rss0;
    rsP[hd * S_ + iw1 + l] = rss1;
  }

  short* po = (p == 0) ? po0 : (p == 1) ? po1 : (p == 2) ? po2 : po3;
#pragma unroll
  for (int dq = 0; dq < 16; ++dq)
#pragma unroll
    for (int r = 0; r < 4; ++r) {
      po[((size_t)(hd * S_ + iw0 + 4 * g + r)) * DH_ + dq * 16 + c16] =
          f2bf(oa0[dq][r]);
      po[((size_t)(hd * S_ + iw1 + 4 * g + r)) * DH_ + dq * 16 + c16] =
          f2bf(oa1[dq][r]);
    }
}

// ---------------------------------------------------------------------------
// Kernel 4: combine 4 bf16 partials -> normalizer + layernorm -> out (f32).
// ---------------------------------------------------------------------------
__global__ __launch_bounds__(256) void combine_kernel(
    const short* __restrict__ po0, const short* __restrict__ po1,
    const short* __restrict__ po2, const short* __restrict__ po3,
    const float* __restrict__ rs0, const float* __restrict__ rs1,
    const float* __restrict__ rs2, const float* __restrict__ rs3,
    const float* __restrict__ fl_arr, const float* __restrict__ scale,
    float* __restrict__ out) {
  int ridx = blockIdx.x * 4 + (threadIdx.x >> 6);
  int lane = threadIdx.x & 63;
  int hd = ridx >> 11, i = ridx & 2047;
  int b = hd >> 2, nh = hd & 3;

  size_t poi = ((size_t)(hd * S_ + i)) * DH_ + lane * 4;
  short4v a4 = *reinterpret_cast<const short4v*>(po0 + poi);
  short4v b4 = *reinterpret_cast<const short4v*>(po1 + poi);
  short4v c4 = *reinterpret_cast<const short4v*>(po2 + poi);
  short4v d4 = *reinterpret_cast<const short4v*>(po3 + poi);

  float rsum = rs0[hd * S_ + i] + rs1[hd * S_ + i] + rs2[hd * S_ + i] +
               rs3[hd * S_ + i];
  float o0 = bf2f(a4[0]) + bf2f(b4[0]) + bf2f(c4[0]) + bf2f(d4[0]);
  float o1 = bf2f(a4[1]) + bf2f(b4[1]) + bf2f(c4[1]) + bf2f(d4[1]);
  float o2 = bf2f(a4[2]) + bf2f(b4[2]) + bf2f(c4[2]) + bf2f(d4[2]);
  float o3 = bf2f(a4[3]) + bf2f(b4[3]) + bf2f(c4[3]) + bf2f(d4[3]);

  float fl = fl_arr[(size_t)hd * S_ + i];
  float inv = 1.f / (fmaxf(fabsf(rsum), fl) + 1e-6f);
  o0 *= inv; o1 *= inv; o2 *= inv; o3 *= inv;

  float s1 = o0 + o1 + o2 + o3;
  float s2 = o0 * o0 + o1 * o1 + o2 * o2 + o3 * o3;
#pragma unroll
  for (int m = 1; m < 64; m <<= 1) {
    s1 += __shfl_xor(s1, m);
    s2 += __shfl_xor(s2, m);
  }
  float mean = s1 * (1.f / DH_);
  float var = s2 * (1.f / DH_) - mean * mean;
  float rstd = rsqrtf(var + 1e-6f);

  const float* scp = scale + nh * DH_ + lane * 4;
  float4 res;
  res.x = (o0 - mean) * rstd * scp[0];
  res.y = (o1 - mean) * rstd * scp[1];
  res.z = (o2 - mean) * rstd * scp[2];
  res.w = (o3 - mean) * rstd * scp[3];
  float* op = out + ((size_t)b * S_ + i) * H_ + nh * DH_ + lane * 4;
  *reinterpret_cast<float4*>(op) = res;
}

// ---------------------------------------------------------------------------
extern "C" void kernel_launch(void* const* d_in, const int* in_sizes, int n_in,
                              void* d_out, int out_size, void* d_ws,
                              size_t ws_size, hipStream_t stream) {
  const float* q   = (const float*)d_in[0];
  const float* k   = (const float*)d_in[1];
  const float* v   = (const float*)d_in[2];
  const float* igk = (const float*)d_in[3];
  const float* igb = (const float*)d_in[4];
  const float* fgk = (const float*)d_in[5];
  const float* fgb = (const float*)d_in[6];
  const float* scl = (const float*)d_in[7];
  float* out = (float*)d_out;

  const size_t seq = (size_t)B_ * NH_ * S_;  // 16384
  const size_t pon = (size_t)8 * 2048 * 256; // elements per partial buffer
  float* ws = (float*)d_ws;
  float* ig_pre = ws;
  float* lsf    = ws + seq;
  float* a_arr  = ws + 2 * seq;
  float* M_arr  = ws + 3 * seq;
  float* fl_arr = ws + 4 * seq;
  float* rs0    = ws + 5 * seq;
  float* rs1    = ws + 6 * seq;
  float* rs2    = ws + 7 * seq;
  float* rs3    = ws + 8 * seq;
  char*  kpack  = (char*)(ws + 9 * seq);                 // 8 MB
  char*  vpack  = kpack + (size_t)8 * 64 * KTILE_BYTES;  // 9.4 MB
  short* po0    = (short*)(vpack + (size_t)8 * 64 * VTILE_BYTES);
  short* po1    = po0 + pon;
  short* po2    = po1 + pon;
  short* po3    = po2 + pon;   // bf16 partials: 4 x 8.4 MB; total ~52 MB

  gates_pack_kernel<<<B_ * S_ + 512, 256, 0, stream>>>(
      q, k, v, igk, igb, fgk, fgb, ig_pre, lsf, kpack, vpack);
  scan_kernel<<<B_ * NH_, 64, 0, stream>>>(ig_pre, lsf, a_arr, M_arr, fl_arr);
  mlstm_mfma<<<512, 256, 0, stream>>>(q, a_arr, M_arr, kpack, vpack,
                                      po0, po1, po2, po3,
                                      rs0, rs1, rs2, rs3);
  combine_kernel<<<B_ * NH_ * S_ / 4, 256, 0, stream>>>(
      po0, po1, po2, po3, rs0, rs1, rs2, rs3, fl_arr, scl, out);
}

// Round 23
// 133.380 us; speedup vs baseline: 1.2339x; 1.1587x over previous
//
#include <hip/hip_runtime.h>
#include <hip/hip_bf16.h>
#include <math.h>

#define B_  2
#define S_  2048
#define H_  1024
#define NH_ 4
#define DH_ 256

typedef __attribute__((ext_vector_type(8))) short short8;
typedef __attribute__((ext_vector_type(4))) short short4v;
typedef __attribute__((ext_vector_type(4))) float f32x4;

#define KTILE_BYTES 16384   // 32 j x 256 d x 2B (swizzled slots)
#define VTILE_BYTES 18432   // 256 d x 36 shorts (transposed, swizzled, padded)

static __device__ __forceinline__ short f2bf(float x) {
  __hip_bfloat16 h = __float2bfloat16(x);
  union { __hip_bfloat16 h; short s; } u;
  u.h = h;
  return u.s;
}

static __device__ __forceinline__ float bf2f(short s) {
  union { unsigned u; float f; } t;
  t.u = ((unsigned)(unsigned short)s) << 16;
  return t.f;
}

static __device__ __forceinline__ short8 pack8(const float4& a, const float4& b) {
  short8 t;
  t[0] = f2bf(a.x); t[1] = f2bf(a.y); t[2] = f2bf(a.z); t[3] = f2bf(a.w);
  t[4] = f2bf(b.x); t[5] = f2bf(b.y); t[6] = f2bf(b.z); t[7] = f2bf(b.w);
  return t;
}

static __device__ __forceinline__ void gload16(const void* g, void* l) {
  __builtin_amdgcn_global_load_lds(
      (const __attribute__((address_space(1))) unsigned int*)g,
      (__attribute__((address_space(3))) unsigned int*)l, 16, 0, 0);
}
static __device__ __forceinline__ void gload4(const void* g, void* l) {
  __builtin_amdgcn_global_load_lds(
      (const __attribute__((address_space(1))) unsigned int*)g,
      (__attribute__((address_space(3))) unsigned int*)l, 4, 0, 0);
}

// ---------------------------------------------------------------------------
// Kernel 1: FUSED gates (blocks 0..1023: 4 rows/block, weights hoisted to
// registers — cuts weight L2 re-reads 390->98 MB) + pack K/V (1024..1535).
// ---------------------------------------------------------------------------
__global__ __launch_bounds__(256) void gates_pack_kernel(
    const float* __restrict__ q, const float* __restrict__ k,
    const float* __restrict__ v,
    const float* __restrict__ igk, const float* __restrict__ igb,
    const float* __restrict__ fgk, const float* __restrict__ fgb,
    float* __restrict__ ig_pre, float* __restrict__ lsf,
    char* __restrict__ kpack, char* __restrict__ vpack) {
  const int bid = blockIdx.x;
  if (bid < (B_ * S_) / 4) {
    // ---- gates path: 4 rows per block ----
    const int b = bid >> 9;               // 512 chunks per batch
    const int s0 = (bid & 511) << 2;
    const int tid = threadIdx.x;
    const int h0 = tid * 4;

    const float4* igk4 = reinterpret_cast<const float4*>(igk);
    const float4* fgk4 = reinterpret_cast<const float4*>(fgk);
    float4 wiq[4], wik[4], wiv[4], wfq[4], wfk[4], wfv[4];
#pragma unroll
    for (int e = 0; e < 4; ++e) {
      int h = h0 + e;
      wiq[e] = igk4[h]; wik[e] = igk4[H_ + h]; wiv[e] = igk4[2 * H_ + h];
      wfq[e] = fgk4[h]; wfk[e] = fgk4[H_ + h]; wfv[e] = fgk4[2 * H_ + h];
    }

    float resI[4][4], resF[4][4];   // [row][gate]
#pragma unroll
    for (int r = 0; r < 4; ++r) {
      int s = s0 + r;
      const float* qrow = q + ((size_t)b * S_ + s) * H_;
      const float* krow = k + ((size_t)b * S_ + s) * H_;
      const float* vrow = v + ((size_t)b * S_ + s) * H_;
      float4 q4 = *reinterpret_cast<const float4*>(qrow + h0);
      float4 k4 = *reinterpret_cast<const float4*>(krow + h0);
      float4 v4 = *reinterpret_cast<const float4*>(vrow + h0);
      float qv[4] = {q4.x, q4.y, q4.z, q4.w};
      float kv[4] = {k4.x, k4.y, k4.z, k4.w};
      float vv[4] = {v4.x, v4.y, v4.z, v4.w};
      float accI[4] = {0.f, 0.f, 0.f, 0.f};
      float accF[4] = {0.f, 0.f, 0.f, 0.f};
#pragma unroll
      for (int e = 0; e < 4; ++e) {
        accI[0] += qv[e] * wiq[e].x + kv[e] * wik[e].x + vv[e] * wiv[e].x;
        accI[1] += qv[e] * wiq[e].y + kv[e] * wik[e].y + vv[e] * wiv[e].y;
        accI[2] += qv[e] * wiq[e].z + kv[e] * wik[e].z + vv[e] * wiv[e].z;
        accI[3] += qv[e] * wiq[e].w + kv[e] * wik[e].w + vv[e] * wiv[e].w;
        accF[0] += qv[e] * wfq[e].x + kv[e] * wfk[e].x + vv[e] * wfv[e].x;
        accF[1] += qv[e] * wfq[e].y + kv[e] * wfk[e].y + vv[e] * wfv[e].y;
        accF[2] += qv[e] * wfq[e].z + kv[e] * wfk[e].z + vv[e] * wfv[e].z;
        accF[3] += qv[e] * wfq[e].w + kv[e] * wfk[e].w + vv[e] * wfv[e].w;
      }
#pragma unroll
      for (int n = 0; n < 4; ++n) {
        for (int m = 1; m < 64; m <<= 1) {
          accI[n] += __shfl_xor(accI[n], m);
          accF[n] += __shfl_xor(accF[n], m);
        }
        resI[r][n] = accI[n];
        resF[r][n] = accF[n];
      }
    }
    __shared__ float red[4][4][8];   // [wave][row][gate: 4 I + 4 F]
    int wave = tid >> 6;
    int lane = tid & 63;
    if (lane == 0) {
#pragma unroll
      for (int r = 0; r < 4; ++r)
#pragma unroll
        for (int n = 0; n < 4; ++n) {
          red[wave][r][n] = resI[r][n];
          red[wave][r][4 + n] = resF[r][n];
        }
    }
    __syncthreads();
    if (tid < 32) {
      int r = tid >> 3, t = tid & 7;
      int s = s0 + r;
      float sum = red[0][r][t] + red[1][r][t] + red[2][r][t] + red[3][r][t];
      if (t < 4) {
        int n = t;
        ig_pre[((size_t)(b * NH_ + n)) * S_ + s] = sum + igb[n];
      } else {
        int n = t - 4;
        float x = sum + fgb[n];
        float ls = (x >= 0.f) ? -log1pf(expf(-x)) : (x - log1pf(expf(x)));
        lsf[((size_t)(b * NH_ + n)) * S_ + s] = ls;
      }
    }
    return;
  }

  // ---- pack path (proven rounds 11-22 layout) ----
  const int bidx = bid - (B_ * S_) / 4;
  const int hd = bidx & 7, jt = bidx >> 3;
  const int b = hd >> 2, nh = hd & 3;
  const float* kgb = k + ((size_t)b * S_ + jt * 32) * H_ + nh * DH_;
  const float* vgb = v + ((size_t)b * S_ + jt * 32) * H_ + nh * DH_;
  char* kp = kpack + ((size_t)(hd * 64 + jt)) * KTILE_BYTES;
  char* vp = vpack + ((size_t)(hd * 64 + jt)) * VTILE_BYTES;
  const int tid = threadIdx.x;

  {
    int j = tid >> 3, sck = tid & 7;
    const float* row = kgb + (size_t)j * H_ + sck * 32;
    short8* out8 = reinterpret_cast<short8*>(kp) + j * 32;
#pragma unroll
    for (int u = 0; u < 4; ++u) {
      float4 a0 = *reinterpret_cast<const float4*>(row + 8 * u);
      float4 a1 = *reinterpret_cast<const float4*>(row + 8 * u + 4);
      out8[(4 * sck + u) ^ (j & 7)] = pack8(a0, a1);
    }
  }
  {
    int d = tid;
    int jsw = ((d >> 4) & 3) << 3;
    short4v* dst = reinterpret_cast<short4v*>(vp + (size_t)d * 72);
#pragma unroll
    for (int c = 0; c < 8; ++c) {
      short4v t;
#pragma unroll
      for (int e = 0; e < 4; ++e)
        t[e] = f2bf(vgb[(size_t)((4 * c + e) ^ jsw) * H_ + d]);
      dst[c] = t;
    }
    short4v z = {0, 0, 0, 0};
    dst[8] = z;
  }
}

// ---------------------------------------------------------------------------
// Kernel 2: per-(b,nh) scan — in-register (proven rounds 6-22).
// ---------------------------------------------------------------------------
__global__ __launch_bounds__(64) void scan_kernel(
    const float* __restrict__ ig_pre, const float* __restrict__ lsf,
    float* __restrict__ a_out, float* __restrict__ M_out,
    float* __restrict__ fl_out) {
  int hd = blockIdx.x;
  int lane = threadIdx.x;
  const float* ig = ig_pre + (size_t)hd * S_;
  const float* ls = lsf + (size_t)hd * S_;
  float xs[32], ys[32];
#pragma unroll
  for (int c = 0; c < 32; ++c) xs[c] = ls[c * 64 + lane];
#pragma unroll
  for (int c = 0; c < 32; ++c) ys[c] = ig[c * 64 + lane];

  float carry = 0.f;
  float mcarry = -INFINITY;
#pragma unroll
  for (int c = 0; c < 32; ++c) {
    int s = c * 64 + lane;
    float x = xs[c];
    for (int off = 1; off < 64; off <<= 1) {
      float t = __shfl_up(x, off);
      if (lane >= off) x += t;
    }
    float csum = carry + x;
    float a = ys[c] - csum;
    float y = a;
    for (int off = 1; off < 64; off <<= 1) {
      float t = __shfl_up(y, off);
      if (lane >= off) y = fmaxf(y, t);
    }
    float M = fmaxf(mcarry, y);
    a_out[(size_t)hd * S_ + s] = a;
    M_out[(size_t)hd * S_ + s] = M;
    fl_out[(size_t)hd * S_ + s] = expf(-(csum + M));
    carry = __shfl(csum, 63);
    mcarry = __shfl(M, 63);
  }
}

// ---------------------------------------------------------------------------
// Kernel 3: MFMA main — R17/R19/R22 chassis (best measured, no setprio).
// 128-row blocks, 4 waves, 2 strips/wave, DMA staging, 4-way parity split,
// bf16 partial stores. LDS: K0|K1|V0|V1 = 69632 B; 2 blocks/CU.
// ---------------------------------------------------------------------------
#define KOFF0 0
#define KOFF1 16384
#define VOFF0 32768
#define VOFF1 51200
#define SMEM_BYTES 69632
#define VSTR 36

__global__ __launch_bounds__(256, 2) void mlstm_mfma(
    const float* __restrict__ q,
    const float* __restrict__ a_arr, const float* __restrict__ M_arr,
    const char* __restrict__ kpack, const char* __restrict__ vpack,
    short* __restrict__ po0, short* __restrict__ po1,
    short* __restrict__ po2, short* __restrict__ po3,
    float* __restrict__ rs0, float* __restrict__ rs1,
    float* __restrict__ rs2, float* __restrict__ rs3) {
  __shared__ __align__(16) char smem[SMEM_BYTES];

  const int bid = blockIdx.x;
  const int half = bid >> 8;
  const int idx = bid & 255;
  const int hd = idx & 7;
  const int u = idx >> 3;  // 0..31
  const int rt = half ? (u & 15) : (15 - (u & 15));
  const int p = half ? (2 + (u >> 4)) : (u >> 4);
  const int ntiles = rt + 1;

  const int b = hd >> 2, nh = hd & 3;
  const int i0 = rt * 128;

  const int tid = threadIdx.x;
  const int wave = tid >> 6;
  const int l = tid & 63;
  const int g = l >> 4;      // 0..3
  const int c16 = l & 15;    // 0..15
  const int iw0 = i0 + wave * 16;        // strip 0 rows
  const int iw1 = i0 + 64 + wave * 16;   // strip 1 rows

  const char* ktiles = kpack + (size_t)hd * 64 * KTILE_BYTES;
  const char* vtiles = vpack + (size_t)hd * 64 * VTILE_BYTES;

  // ---- Q fragments (B-operand), two strips ----
  short8 qf0[8], qf1[8];
  {
    const float* qp0 = q + ((size_t)b * S_ + (iw0 + c16)) * H_ + nh * DH_;
    const float* qp1 = q + ((size_t)b * S_ + (iw1 + c16)) * H_ + nh * DH_;
#pragma unroll
    for (int c = 0; c < 8; ++c) {
      int d0 = c * 32 + g * 8;
      qf0[c] = pack8(*reinterpret_cast<const float4*>(qp0 + d0),
                     *reinterpret_cast<const float4*>(qp0 + d0 + 4));
      qf1[c] = pack8(*reinterpret_cast<const float4*>(qp1 + d0),
                     *reinterpret_cast<const float4*>(qp1 + d0 + 4));
    }
  }
  const float Mrs0 = M_arr[(size_t)hd * S_ + iw0 + c16];
  const float Mrs1 = M_arr[(size_t)hd * S_ + iw1 + c16];
  const int i_row0 = iw0 + c16;
  const int i_row1 = iw1 + c16;

  f32x4 oa0[16], oa1[16];
#pragma unroll
  for (int d = 0; d < 16; ++d) {
    oa0[d] = (f32x4){0.f, 0.f, 0.f, 0.f};
    oa1[d] = (f32x4){0.f, 0.f, 0.f, 0.f};
  }
  float rss0 = 0.f, rss1 = 0.f;

  const float* agb = a_arr + (size_t)hd * S_;

  auto stage = [&](int jt, int buf) {
    const char* kt = ktiles + (size_t)jt * KTILE_BYTES + wave * 4096;
    char* kl = smem + (buf ? KOFF1 : KOFF0) + wave * 4096;
#pragma unroll
    for (int uu = 0; uu < 4; ++uu)
      gload16(kt + uu * 1024 + l * 16, kl + uu * 1024);
    const char* vt = vtiles + (size_t)jt * VTILE_BYTES + wave * 4608;
    char* vl = smem + (buf ? VOFF1 : VOFF0) + wave * 4608;
#pragma unroll
    for (int uu = 0; uu < 4; ++uu)
      gload16(vt + uu * 1024 + l * 16, vl + uu * 1024);
#pragma unroll
    for (int uu = 0; uu < 2; ++uu)
      gload4(vt + 4096 + uu * 256 + l * 4, vl + 4096 + uu * 256);
  };

  stage(p, 0);
  __syncthreads();

  for (int n = 0; n < ntiles; ++n) {
    const int jt = p + 4 * n;
    const int cur = n & 1;
    if (n + 1 < ntiles) stage(jt + 4, cur ^ 1);  // DMA in flight over compute

    {
      const int j0 = jt * 32;
      const short8* kb8 =
          reinterpret_cast<const short8*>(smem + (cur ? KOFF1 : KOFF0));
      const short* vt =
          reinterpret_cast<const short*>(smem + (cur ? VOFF1 : VOFF0));
      // ---- S^T = K Q (swapped), both strips; kf loaded once ----
      f32x4 sa0 = {0.f, 0.f, 0.f, 0.f}, sa1 = {0.f, 0.f, 0.f, 0.f};
      f32x4 sb0 = {0.f, 0.f, 0.f, 0.f}, sb1 = {0.f, 0.f, 0.f, 0.f};
#pragma unroll
      for (int c = 0; c < 8; ++c) {
        int row0 = c16, row1 = 16 + c16;
        int slot = 4 * c + g;
        short8 kf0 = kb8[row0 * 32 + (slot ^ (row0 & 7))];
        short8 kf1 = kb8[row1 * 32 + (slot ^ (row1 & 7))];
        sa0 = __builtin_amdgcn_mfma_f32_16x16x32_bf16(kf0, qf0[c], sa0, 0, 0, 0);
        sa1 = __builtin_amdgcn_mfma_f32_16x16x32_bf16(kf1, qf0[c], sa1, 0, 0, 0);
        sb0 = __builtin_amdgcn_mfma_f32_16x16x32_bf16(kf0, qf1[c], sb0, 0, 0, 0);
        sb1 = __builtin_amdgcn_mfma_f32_16x16x32_bf16(kf1, qf1[c], sb1, 0, 0, 0);
      }
      // ---- weights, causal mask, rowsums (per-lane) ----
      float4 av0 = *reinterpret_cast<const float4*>(agb + j0 + 4 * g);
      float4 av1 = *reinterpret_cast<const float4*>(agb + j0 + 16 + 4 * g);
      float w00[4], w01[4], w10[4], w11[4];
#pragma unroll
      for (int r = 0; r < 4; ++r) {
        float aa0 = reinterpret_cast<const float*>(&av0)[r];
        float aa1 = reinterpret_cast<const float*>(&av1)[r];
        int j_0 = j0 + 4 * g + r, j_1 = j0 + 16 + 4 * g + r;
        float e00 = __expf(aa0 - Mrs0), e01 = __expf(aa1 - Mrs0);
        float e10 = __expf(aa0 - Mrs1), e11 = __expf(aa1 - Mrs1);
        float t;
        t = sa0[r] * 0.0625f * e00; w00[r] = (j_0 <= i_row0) ? t : 0.f;
        t = sa1[r] * 0.0625f * e01; w01[r] = (j_1 <= i_row0) ? t : 0.f;
        t = sb0[r] * 0.0625f * e10; w10[r] = (j_0 <= i_row1) ? t : 0.f;
        t = sb1[r] * 0.0625f * e11; w11[r] = (j_1 <= i_row1) ? t : 0.f;
        rss0 += w00[r] + w01[r];
        rss1 += w10[r] + w11[r];
      }
      // ---- P -> bf16 pairs in-register, both strips ----
      unsigned pA0, pB0, pC0, pD0, pA1, pB1, pC1, pD1;
      asm("v_cvt_pk_bf16_f32 %0, %1, %2" : "=v"(pA0) : "v"(w00[0]), "v"(w00[1]));
      asm("v_cvt_pk_bf16_f32 %0, %1, %2" : "=v"(pB0) : "v"(w00[2]), "v"(w00[3]));
      asm("v_cvt_pk_bf16_f32 %0, %1, %2" : "=v"(pC0) : "v"(w01[0]), "v"(w01[1]));
      asm("v_cvt_pk_bf16_f32 %0, %1, %2" : "=v"(pD0) : "v"(w01[2]), "v"(w01[3]));
      asm("v_cvt_pk_bf16_f32 %0, %1, %2" : "=v"(pA1) : "v"(w10[0]), "v"(w10[1]));
      asm("v_cvt_pk_bf16_f32 %0, %1, %2" : "=v"(pB1) : "v"(w10[2]), "v"(w10[3]));
      asm("v_cvt_pk_bf16_f32 %0, %1, %2" : "=v"(pC1) : "v"(w11[0]), "v"(w11[1]));
      asm("v_cvt_pk_bf16_f32 %0, %1, %2" : "=v"(pD1) : "v"(w11[2]), "v"(w11[3]));
      // ---- gather PV A-frags: P[i=c16][j=8g..8g+7] per strip ----
      int src0 = 32 * (g & 1) + c16;
      int src1 = src0 + 16;
      bool lo = (g < 2);
      union { int u[4]; short8 s; } pu0, pu1;
      {
        int a0s = __shfl((int)pA0, src0, 64), b0s = __shfl((int)pB0, src0, 64);
        int c0s = __shfl((int)pC0, src0, 64), d0s = __shfl((int)pD0, src0, 64);
        int a1s = __shfl((int)pA0, src1, 64), b1s = __shfl((int)pB0, src1, 64);
        int c1s = __shfl((int)pC0, src1, 64), d1s = __shfl((int)pD0, src1, 64);
        pu0.u[0] = lo ? a0s : c0s;
        pu0.u[1] = lo ? b0s : d0s;
        pu0.u[2] = lo ? a1s : c1s;
        pu0.u[3] = lo ? b1s : d1s;
      }
      {
        int a0s = __shfl((int)pA1, src0, 64), b0s = __shfl((int)pB1, src0, 64);
        int c0s = __shfl((int)pC1, src0, 64), d0s = __shfl((int)pD1, src0, 64);
        int a1s = __shfl((int)pA1, src1, 64), b1s = __shfl((int)pB1, src1, 64);
        int c1s = __shfl((int)pC1, src1, 64), d1s = __shfl((int)pD1, src1, 64);
        pu1.u[0] = lo ? a0s : c0s;
        pu1.u[1] = lo ? b0s : d0s;
        pu1.u[2] = lo ? a1s : c1s;
        pu1.u[3] = lo ? b1s : d1s;
      }
      short8 pa0 = pu0.s, pa1 = pu1.s;
      // ---- O += P V; vf loaded once, used by both strips ----
#pragma unroll
      for (int dq = 0; dq < 16; ++dq) {
        short8 vf = *reinterpret_cast<const short8*>(
            vt + (16 * dq + c16) * VSTR + 8 * (g ^ (dq & 3)));
        oa0[dq] = __builtin_amdgcn_mfma_f32_16x16x32_bf16(pa0, vf, oa0[dq], 0, 0, 0);
        oa1[dq] = __builtin_amdgcn_mfma_f32_16x16x32_bf16(pa1, vf, oa1[dq], 0, 0, 0);
      }
    }
    __syncthreads();  // drains vmcnt (next tile landed) + all LDS reads done
  }

  // ---- rowsum reduce across g-groups (same c16) ----
  rss0 += __shfl_xor(rss0, 16);
  rss0 += __shfl_xor(rss0, 32);
  rss1 += __shfl_xor(rss1, 16);
  rss1 += __shfl_xor(rss1, 32);

  float* rsP = (p == 0) ? rs0 : (p == 1) ? rs1 : (p == 2) ? rs2 : rs3;
  if (l < 16) {
    rsP[hd * S_ + iw0 + l] = rss0;
    rsP[hd * S_ + iw1 + l] = rss1;
  }

  short* po = (p == 0) ? po0 : (p == 1) ? po1 : (p == 2) ? po2 : po3;
#pragma unroll
  for (int dq = 0; dq < 16; ++dq)
#pragma unroll
    for (int r = 0; r < 4; ++r) {
      po[((size_t)(hd * S_ + iw0 + 4 * g + r)) * DH_ + dq * 16 + c16] =
          f2bf(oa0[dq][r]);
      po[((size_t)(hd * S_ + iw1 + 4 * g + r)) * DH_ + dq * 16 + c16] =
          f2bf(oa1[dq][r]);
    }
}

// ---------------------------------------------------------------------------
// Kernel 4: combine 4 bf16 partials -> normalizer + layernorm -> out (f32).
// ---------------------------------------------------------------------------
__global__ __launch_bounds__(256) void combine_kernel(
    const short* __restrict__ po0, const short* __restrict__ po1,
    const short* __restrict__ po2, const short* __restrict__ po3,
    const float* __restrict__ rs0, const float* __restrict__ rs1,
    const float* __restrict__ rs2, const float* __restrict__ rs3,
    const float* __restrict__ fl_arr, const float* __restrict__ scale,
    float* __restrict__ out) {
  int ridx = blockIdx.x * 4 + (threadIdx.x >> 6);
  int lane = threadIdx.x & 63;
  int hd = ridx >> 11, i = ridx & 2047;
  int b = hd >> 2, nh = hd & 3;

  size_t poi = ((size_t)(hd * S_ + i)) * DH_ + lane * 4;
  short4v a4 = *reinterpret_cast<const short4v*>(po0 + poi);
  short4v b4 = *reinterpret_cast<const short4v*>(po1 + poi);
  short4v c4 = *reinterpret_cast<const short4v*>(po2 + poi);
  short4v d4 = *reinterpret_cast<const short4v*>(po3 + poi);

  float rsum = rs0[hd * S_ + i] + rs1[hd * S_ + i] + rs2[hd * S_ + i] +
               rs3[hd * S_ + i];
  float o0 = bf2f(a4[0]) + bf2f(b4[0]) + bf2f(c4[0]) + bf2f(d4[0]);
  float o1 = bf2f(a4[1]) + bf2f(b4[1]) + bf2f(c4[1]) + bf2f(d4[1]);
  float o2 = bf2f(a4[2]) + bf2f(b4[2]) + bf2f(c4[2]) + bf2f(d4[2]);
  float o3 = bf2f(a4[3]) + bf2f(b4[3]) + bf2f(c4[3]) + bf2f(d4[3]);

  float fl = fl_arr[(size_t)hd * S_ + i];
  float inv = 1.f / (fmaxf(fabsf(rsum), fl) + 1e-6f);
  o0 *= inv; o1 *= inv; o2 *= inv; o3 *= inv;

  float s1 = o0 + o1 + o2 + o3;
  float s2 = o0 * o0 + o1 * o1 + o2 * o2 + o3 * o3;
#pragma unroll
  for (int m = 1; m < 64; m <<= 1) {
    s1 += __shfl_xor(s1, m);
    s2 += __shfl_xor(s2, m);
  }
  float mean = s1 * (1.f / DH_);
  float var = s2 * (1.f / DH_) - mean * mean;
  float rstd = rsqrtf(var + 1e-6f);

  const float* scp = scale + nh * DH_ + lane * 4;
  float4 res;
  res.x = (o0 - mean) * rstd * scp[0];
  res.y = (o1 - mean) * rstd * scp[1];
  res.z = (o2 - mean) * rstd * scp[2];
  res.w = (o3 - mean) * rstd * scp[3];
  float* op = out + ((size_t)b * S_ + i) * H_ + nh * DH_ + lane * 4;
  *reinterpret_cast<float4*>(op) = res;
}

// ---------------------------------------------------------------------------
extern "C" void kernel_launch(void* const* d_in, const int* in_sizes, int n_in,
                              void* d_out, int out_size, void* d_ws,
                              size_t ws_size, hipStream_t stream) {
  const float* q   = (const float*)d_in[0];
  const float* k   = (const float*)d_in[1];
  const float* v   = (const float*)d_in[2];
  const float* igk = (const float*)d_in[3];
  const float* igb = (const float*)d_in[4];
  const float* fgk = (const float*)d_in[5];
  const float* fgb = (const float*)d_in[6];
  const float* scl = (const float*)d_in[7];
  float* out = (float*)d_out;

  const size_t seq = (size_t)B_ * NH_ * S_;  // 16384
  const size_t pon = (size_t)8 * 2048 * 256; // elements per partial buffer
  float* ws = (float*)d_ws;
  float* ig_pre = ws;
  float* lsf    = ws + seq;
  float* a_arr  = ws + 2 * seq;
  float* M_arr  = ws + 3 * seq;
  float* fl_arr = ws + 4 * seq;
  float* rs0    = ws + 5 * seq;
  float* rs1    = ws + 6 * seq;
  float* rs2    = ws + 7 * seq;
  float* rs3    = ws + 8 * seq;
  char*  kpack  = (char*)(ws + 9 * seq);                 // 8 MB
  char*  vpack  = kpack + (size_t)8 * 64 * KTILE_BYTES;  // 9.4 MB
  short* po0    = (short*)(vpack + (size_t)8 * 64 * VTILE_BYTES);
  short* po1    = po0 + pon;
  short* po2    = po1 + pon;
  short* po3    = po2 + pon;   // bf16 partials: 4 x 8.4 MB; total ~52 MB

  gates_pack_kernel<<<(B_ * S_) / 4 + 512, 256, 0, stream>>>(
      q, k, v, igk, igb, fgk, fgb, ig_pre, lsf, kpack, vpack);
  scan_kernel<<<B_ * NH_, 64, 0, stream>>>(ig_pre, lsf, a_arr, M_arr, fl_arr);
  mlstm_mfma<<<512, 256, 0, stream>>>(q, a_arr, M_arr, kpack, vpack,
                                      po0, po1, po2, po3,
                                      rs0, rs1, rs2, rs3);
  combine_kernel<<<B_ * NH_ * S_ / 4, 256, 0, stream>>>(
      po0, po1, po2, po3, rs0, rs1, rs2, rs3, fl_arr, scl, out);
}

// Round 24
// 131.213 us; speedup vs baseline: 1.2543x; 1.0165x over previous
//
#include <hip/hip_runtime.h>
#include <hip/hip_bf16.h>
#include <math.h>

#define B_  2
#define S_  2048
#define H_  1024
#define NH_ 4
#define DH_ 256

typedef __attribute__((ext_vector_type(8))) short short8;
typedef __attribute__((ext_vector_type(4))) short short4v;
typedef __attribute__((ext_vector_type(4))) float f32x4;

#define KTILE_BYTES 16384   // 32 j x 256 d x 2B (swizzled slots)
#define VTILE_BYTES 18432   // 256 d x 36 shorts (transposed, swizzled, padded)

static __device__ __forceinline__ short f2bf(float x) {
  __hip_bfloat16 h = __float2bfloat16(x);
  union { __hip_bfloat16 h; short s; } u;
  u.h = h;
  return u.s;
}

static __device__ __forceinline__ float bf2f(short s) {
  union { unsigned u; float f; } t;
  t.u = ((unsigned)(unsigned short)s) << 16;
  return t.f;
}

static __device__ __forceinline__ short8 pack8(const float4& a, const float4& b) {
  short8 t;
  t[0] = f2bf(a.x); t[1] = f2bf(a.y); t[2] = f2bf(a.z); t[3] = f2bf(a.w);
  t[4] = f2bf(b.x); t[5] = f2bf(b.y); t[6] = f2bf(b.z); t[7] = f2bf(b.w);
  return t;
}

static __device__ __forceinline__ void gload16(const void* g, void* l) {
  __builtin_amdgcn_global_load_lds(
      (const __attribute__((address_space(1))) unsigned int*)g,
      (__attribute__((address_space(3))) unsigned int*)l, 16, 0, 0);
}
static __device__ __forceinline__ void gload4(const void* g, void* l) {
  __builtin_amdgcn_global_load_lds(
      (const __attribute__((address_space(1))) unsigned int*)g,
      (__attribute__((address_space(3))) unsigned int*)l, 4, 0, 0);
}

// ---------------------------------------------------------------------------
// Kernel 1: FUSED gates + pack, single pass over q/k/v (1024 blocks, 4 rows
// each). Pack images are written straight from the gates path's registers:
//   K image byte  = j*512 + ((dsl>>3)^(j&7))*16 + (dsl&7)*2   (8B store/row)
//   V image short = d*36 + (j ^ jsw), jsw=((d>>4)&3)<<3; a 4-aligned j-run
//   stays contiguous under the XOR -> one 8B store per d.
// Images are byte-identical to the R23 pack kernel (pad shorts 32..35 per d
// are never read by main's vf indexing, so left uninitialized).
// ---------------------------------------------------------------------------
__global__ __launch_bounds__(256) void gates_pack_kernel(
    const float* __restrict__ q, const float* __restrict__ k,
    const float* __restrict__ v,
    const float* __restrict__ igk, const float* __restrict__ igb,
    const float* __restrict__ fgk, const float* __restrict__ fgb,
    float* __restrict__ ig_pre, float* __restrict__ lsf,
    char* __restrict__ kpack, char* __restrict__ vpack) {
  const int bid = blockIdx.x;           // 0..1023
  const int b = bid >> 9;               // 512 chunks per batch
  const int s0 = (bid & 511) << 2;      // first of 4 rows (4-aligned)
  const int tid = threadIdx.x;
  const int h0 = tid * 4;
  const int nh = h0 >> 8;               // head of this thread's d-slice
  const int dsl = h0 & 255;             // d-slice base within head
  const int hd = b * 4 + nh;
  const int jt = s0 >> 5;
  const int j0 = s0 & 31;               // j_local base (4-aligned)

  char* kp = kpack + ((size_t)(hd * 64 + jt)) * KTILE_BYTES;
  char* vp = vpack + ((size_t)(hd * 64 + jt)) * VTILE_BYTES;

  const float4* igk4 = reinterpret_cast<const float4*>(igk);
  const float4* fgk4 = reinterpret_cast<const float4*>(fgk);
  float4 wiq[4], wik[4], wiv[4], wfq[4], wfk[4], wfv[4];
#pragma unroll
  for (int e = 0; e < 4; ++e) {
    int h = h0 + e;
    wiq[e] = igk4[h]; wik[e] = igk4[H_ + h]; wiv[e] = igk4[2 * H_ + h];
    wfq[e] = fgk4[h]; wfk[e] = fgk4[H_ + h]; wfv[e] = fgk4[2 * H_ + h];
  }

  float vrows[4][4];              // [row][e] for the V-image writes
  float resI[4][4], resF[4][4];   // [row][gate]
#pragma unroll
  for (int r = 0; r < 4; ++r) {
    int s = s0 + r;
    const float* qrow = q + ((size_t)b * S_ + s) * H_;
    const float* krow = k + ((size_t)b * S_ + s) * H_;
    const float* vrow = v + ((size_t)b * S_ + s) * H_;
    float4 q4 = *reinterpret_cast<const float4*>(qrow + h0);
    float4 k4 = *reinterpret_cast<const float4*>(krow + h0);
    float4 v4 = *reinterpret_cast<const float4*>(vrow + h0);
    float qv[4] = {q4.x, q4.y, q4.z, q4.w};
    float kv[4] = {k4.x, k4.y, k4.z, k4.w};
    float vv[4] = {v4.x, v4.y, v4.z, v4.w};
#pragma unroll
    for (int e = 0; e < 4; ++e) vrows[r][e] = vv[e];

    // ---- K image write (8B: 4 bf16 of this row's d-slice) ----
    {
      int j = j0 + r;
      short4v ks;
      ks[0] = f2bf(kv[0]); ks[1] = f2bf(kv[1]);
      ks[2] = f2bf(kv[2]); ks[3] = f2bf(kv[3]);
      *reinterpret_cast<short4v*>(
          kp + j * 512 + (((dsl >> 3) ^ (j & 7)) << 4) + (dsl & 7) * 2) = ks;
    }

    float accI[4] = {0.f, 0.f, 0.f, 0.f};
    float accF[4] = {0.f, 0.f, 0.f, 0.f};
#pragma unroll
    for (int e = 0; e < 4; ++e) {
      accI[0] += qv[e] * wiq[e].x + kv[e] * wik[e].x + vv[e] * wiv[e].x;
      accI[1] += qv[e] * wiq[e].y + kv[e] * wik[e].y + vv[e] * wiv[e].y;
      accI[2] += qv[e] * wiq[e].z + kv[e] * wik[e].z + vv[e] * wiv[e].z;
      accI[3] += qv[e] * wiq[e].w + kv[e] * wik[e].w + vv[e] * wiv[e].w;
      accF[0] += qv[e] * wfq[e].x + kv[e] * wfk[e].x + vv[e] * wfv[e].x;
      accF[1] += qv[e] * wfq[e].y + kv[e] * wfk[e].y + vv[e] * wfv[e].y;
      accF[2] += qv[e] * wfq[e].z + kv[e] * wfk[e].z + vv[e] * wfv[e].z;
      accF[3] += qv[e] * wfq[e].w + kv[e] * wfk[e].w + vv[e] * wfv[e].w;
    }
#pragma unroll
    for (int n = 0; n < 4; ++n) {
      for (int m = 1; m < 64; m <<= 1) {
        accI[n] += __shfl_xor(accI[n], m);
        accF[n] += __shfl_xor(accF[n], m);
      }
      resI[r][n] = accI[n];
      resF[r][n] = accF[n];
    }
  }

  // ---- V image writes: per d, the 4-row bf16 run at m0 = j0 ^ jsw ----
  {
    int jsw = ((dsl >> 4) & 3) << 3;   // constant across e (dsl % 4 == 0)
    int m0 = j0 ^ jsw;
#pragma unroll
    for (int e = 0; e < 4; ++e) {
      int d = dsl + e;
      short4v t;
      t[0] = f2bf(vrows[0][e]); t[1] = f2bf(vrows[1][e]);
      t[2] = f2bf(vrows[2][e]); t[3] = f2bf(vrows[3][e]);
      *reinterpret_cast<short4v*>(vp + (size_t)d * 72 + m0 * 2) = t;
    }
  }

  __shared__ float red[4][4][8];   // [wave][row][gate: 4 I + 4 F]
  int wave = tid >> 6;
  int lane = tid & 63;
  if (lane == 0) {
#pragma unroll
    for (int r = 0; r < 4; ++r)
#pragma unroll
      for (int n = 0; n < 4; ++n) {
        red[wave][r][n] = resI[r][n];
        red[wave][r][4 + n] = resF[r][n];
      }
  }
  __syncthreads();
  if (tid < 32) {
    int r = tid >> 3, t = tid & 7;
    int s = s0 + r;
    float sum = red[0][r][t] + red[1][r][t] + red[2][r][t] + red[3][r][t];
    if (t < 4) {
      int n = t;
      ig_pre[((size_t)(b * NH_ + n)) * S_ + s] = sum + igb[n];
    } else {
      int n = t - 4;
      float x = sum + fgb[n];
      float ls = (x >= 0.f) ? -log1pf(expf(-x)) : (x - log1pf(expf(x)));
      lsf[((size_t)(b * NH_ + n)) * S_ + s] = ls;
    }
  }
}

// ---------------------------------------------------------------------------
// Kernel 2: per-(b,nh) scan — in-register (proven rounds 6-23).
// ---------------------------------------------------------------------------
__global__ __launch_bounds__(64) void scan_kernel(
    const float* __restrict__ ig_pre, const float* __restrict__ lsf,
    float* __restrict__ a_out, float* __restrict__ M_out,
    float* __restrict__ fl_out) {
  int hd = blockIdx.x;
  int lane = threadIdx.x;
  const float* ig = ig_pre + (size_t)hd * S_;
  const float* ls = lsf + (size_t)hd * S_;
  float xs[32], ys[32];
#pragma unroll
  for (int c = 0; c < 32; ++c) xs[c] = ls[c * 64 + lane];
#pragma unroll
  for (int c = 0; c < 32; ++c) ys[c] = ig[c * 64 + lane];

  float carry = 0.f;
  float mcarry = -INFINITY;
#pragma unroll
  for (int c = 0; c < 32; ++c) {
    int s = c * 64 + lane;
    float x = xs[c];
    for (int off = 1; off < 64; off <<= 1) {
      float t = __shfl_up(x, off);
      if (lane >= off) x += t;
    }
    float csum = carry + x;
    float a = ys[c] - csum;
    float y = a;
    for (int off = 1; off < 64; off <<= 1) {
      float t = __shfl_up(y, off);
      if (lane >= off) y = fmaxf(y, t);
    }
    float M = fmaxf(mcarry, y);
    a_out[(size_t)hd * S_ + s] = a;
    M_out[(size_t)hd * S_ + s] = M;
    fl_out[(size_t)hd * S_ + s] = expf(-(csum + M));
    carry = __shfl(csum, 63);
    mcarry = __shfl(M, 63);
  }
}

// ---------------------------------------------------------------------------
// Kernel 3: MFMA main — R17/R19/R22 chassis (best measured, no setprio).
// 128-row blocks, 4 waves, 2 strips/wave, DMA staging, 4-way parity split,
// bf16 partial stores. LDS: K0|K1|V0|V1 = 69632 B; 2 blocks/CU.
// ---------------------------------------------------------------------------
#define KOFF0 0
#define KOFF1 16384
#define VOFF0 32768
#define VOFF1 51200
#define SMEM_BYTES 69632
#define VSTR 36

__global__ __launch_bounds__(256, 2) void mlstm_mfma(
    const float* __restrict__ q,
    const float* __restrict__ a_arr, const float* __restrict__ M_arr,
    const char* __restrict__ kpack, const char* __restrict__ vpack,
    short* __restrict__ po0, short* __restrict__ po1,
    short* __restrict__ po2, short* __restrict__ po3,
    float* __restrict__ rs0, float* __restrict__ rs1,
    float* __restrict__ rs2, float* __restrict__ rs3) {
  __shared__ __align__(16) char smem[SMEM_BYTES];

  const int bid = blockIdx.x;
  const int half = bid >> 8;
  const int idx = bid & 255;
  const int hd = idx & 7;
  const int u = idx >> 3;  // 0..31
  const int rt = half ? (u & 15) : (15 - (u & 15));
  const int p = half ? (2 + (u >> 4)) : (u >> 4);
  const int ntiles = rt + 1;

  const int b = hd >> 2, nh = hd & 3;
  const int i0 = rt * 128;

  const int tid = threadIdx.x;
  const int wave = tid >> 6;
  const int l = tid & 63;
  const int g = l >> 4;      // 0..3
  const int c16 = l & 15;    // 0..15
  const int iw0 = i0 + wave * 16;        // strip 0 rows
  const int iw1 = i0 + 64 + wave * 16;   // strip 1 rows

  const char* ktiles = kpack + (size_t)hd * 64 * KTILE_BYTES;
  const char* vtiles = vpack + (size_t)hd * 64 * VTILE_BYTES;

  // ---- Q fragments (B-operand), two strips ----
  short8 qf0[8], qf1[8];
  {
    const float* qp0 = q + ((size_t)b * S_ + (iw0 + c16)) * H_ + nh * DH_;
    const float* qp1 = q + ((size_t)b * S_ + (iw1 + c16)) * H_ + nh * DH_;
#pragma unroll
    for (int c = 0; c < 8; ++c) {
      int d0 = c * 32 + g * 8;
      qf0[c] = pack8(*reinterpret_cast<const float4*>(qp0 + d0),
                     *reinterpret_cast<const float4*>(qp0 + d0 + 4));
      qf1[c] = pack8(*reinterpret_cast<const float4*>(qp1 + d0),
                     *reinterpret_cast<const float4*>(qp1 + d0 + 4));
    }
  }
  const float Mrs0 = M_arr[(size_t)hd * S_ + iw0 + c16];
  const float Mrs1 = M_arr[(size_t)hd * S_ + iw1 + c16];
  const int i_row0 = iw0 + c16;
  const int i_row1 = iw1 + c16;

  f32x4 oa0[16], oa1[16];
#pragma unroll
  for (int d = 0; d < 16; ++d) {
    oa0[d] = (f32x4){0.f, 0.f, 0.f, 0.f};
    oa1[d] = (f32x4){0.f, 0.f, 0.f, 0.f};
  }
  float rss0 = 0.f, rss1 = 0.f;

  const float* agb = a_arr + (size_t)hd * S_;

  auto stage = [&](int jt, int buf) {
    const char* kt = ktiles + (size_t)jt * KTILE_BYTES + wave * 4096;
    char* kl = smem + (buf ? KOFF1 : KOFF0) + wave * 4096;
#pragma unroll
    for (int uu = 0; uu < 4; ++uu)
      gload16(kt + uu * 1024 + l * 16, kl + uu * 1024);
    const char* vt = vtiles + (size_t)jt * VTILE_BYTES + wave * 4608;
    char* vl = smem + (buf ? VOFF1 : VOFF0) + wave * 4608;
#pragma unroll
    for (int uu = 0; uu < 4; ++uu)
      gload16(vt + uu * 1024 + l * 16, vl + uu * 1024);
#pragma unroll
    for (int uu = 0; uu < 2; ++uu)
      gload4(vt + 4096 + uu * 256 + l * 4, vl + 4096 + uu * 256);
  };

  stage(p, 0);
  __syncthreads();

  for (int n = 0; n < ntiles; ++n) {
    const int jt = p + 4 * n;
    const int cur = n & 1;
    if (n + 1 < ntiles) stage(jt + 4, cur ^ 1);  // DMA in flight over compute

    {
      const int j0 = jt * 32;
      const short8* kb8 =
          reinterpret_cast<const short8*>(smem + (cur ? KOFF1 : KOFF0));
      const short* vt =
          reinterpret_cast<const short*>(smem + (cur ? VOFF1 : VOFF0));
      // ---- S^T = K Q (swapped), both strips; kf loaded once ----
      f32x4 sa0 = {0.f, 0.f, 0.f, 0.f}, sa1 = {0.f, 0.f, 0.f, 0.f};
      f32x4 sb0 = {0.f, 0.f, 0.f, 0.f}, sb1 = {0.f, 0.f, 0.f, 0.f};
#pragma unroll
      for (int c = 0; c < 8; ++c) {
        int row0 = c16, row1 = 16 + c16;
        int slot = 4 * c + g;
        short8 kf0 = kb8[row0 * 32 + (slot ^ (row0 & 7))];
        short8 kf1 = kb8[row1 * 32 + (slot ^ (row1 & 7))];
        sa0 = __builtin_amdgcn_mfma_f32_16x16x32_bf16(kf0, qf0[c], sa0, 0, 0, 0);
        sa1 = __builtin_amdgcn_mfma_f32_16x16x32_bf16(kf1, qf0[c], sa1, 0, 0, 0);
        sb0 = __builtin_amdgcn_mfma_f32_16x16x32_bf16(kf0, qf1[c], sb0, 0, 0, 0);
        sb1 = __builtin_amdgcn_mfma_f32_16x16x32_bf16(kf1, qf1[c], sb1, 0, 0, 0);
      }
      // ---- weights, causal mask, rowsums (per-lane) ----
      float4 av0 = *reinterpret_cast<const float4*>(agb + j0 + 4 * g);
      float4 av1 = *reinterpret_cast<const float4*>(agb + j0 + 16 + 4 * g);
      float w00[4], w01[4], w10[4], w11[4];
#pragma unroll
      for (int r = 0; r < 4; ++r) {
        float aa0 = reinterpret_cast<const float*>(&av0)[r];
        float aa1 = reinterpret_cast<const float*>(&av1)[r];
        int j_0 = j0 + 4 * g + r, j_1 = j0 + 16 + 4 * g + r;
        float e00 = __expf(aa0 - Mrs0), e01 = __expf(aa1 - Mrs0);
        float e10 = __expf(aa0 - Mrs1), e11 = __expf(aa1 - Mrs1);
        float t;
        t = sa0[r] * 0.0625f * e00; w00[r] = (j_0 <= i_row0) ? t : 0.f;
        t = sa1[r] * 0.0625f * e01; w01[r] = (j_1 <= i_row0) ? t : 0.f;
        t = sb0[r] * 0.0625f * e10; w10[r] = (j_0 <= i_row1) ? t : 0.f;
        t = sb1[r] * 0.0625f * e11; w11[r] = (j_1 <= i_row1) ? t : 0.f;
        rss0 += w00[r] + w01[r];
        rss1 += w10[r] + w11[r];
      }
      // ---- P -> bf16 pairs in-register, both strips ----
      unsigned pA0, pB0, pC0, pD0, pA1, pB1, pC1, pD1;
      asm("v_cvt_pk_bf16_f32 %0, %1, %2" : "=v"(pA0) : "v"(w00[0]), "v"(w00[1]));
      asm("v_cvt_pk_bf16_f32 %0, %1, %2" : "=v"(pB0) : "v"(w00[2]), "v"(w00[3]));
      asm("v_cvt_pk_bf16_f32 %0, %1, %2" : "=v"(pC0) : "v"(w01[0]), "v"(w01[1]));
      asm("v_cvt_pk_bf16_f32 %0, %1, %2" : "=v"(pD0) : "v"(w01[2]), "v"(w01[3]));
      asm("v_cvt_pk_bf16_f32 %0, %1, %2" : "=v"(pA1) : "v"(w10[0]), "v"(w10[1]));
      asm("v_cvt_pk_bf16_f32 %0, %1, %2" : "=v"(pB1) : "v"(w10[2]), "v"(w10[3]));
      asm("v_cvt_pk_bf16_f32 %0, %1, %2" : "=v"(pC1) : "v"(w11[0]), "v"(w11[1]));
      asm("v_cvt_pk_bf16_f32 %0, %1, %2" : "=v"(pD1) : "v"(w11[2]), "v"(w11[3]));
      // ---- gather PV A-frags: P[i=c16][j=8g..8g+7] per strip ----
      int src0 = 32 * (g & 1) + c16;
      int src1 = src0 + 16;
      bool lo = (g < 2);
      union { int u[4]; short8 s; } pu0, pu1;
      {
        int a0s = __shfl((int)pA0, src0, 64), b0s = __shfl((int)pB0, src0, 64);
        int c0s = __shfl((int)pC0, src0, 64), d0s = __shfl((int)pD0, src0, 64);
        int a1s = __shfl((int)pA0, src1, 64), b1s = __shfl((int)pB0, src1, 64);
        int c1s = __shfl((int)pC0, src1, 64), d1s = __shfl((int)pD0, src1, 64);
        pu0.u[0] = lo ? a0s : c0s;
        pu0.u[1] = lo ? b0s : d0s;
        pu0.u[2] = lo ? a1s : c1s;
        pu0.u[3] = lo ? b1s : d1s;
      }
      {
        int a0s = __shfl((int)pA1, src0, 64), b0s = __shfl((int)pB1, src0, 64);
        int c0s = __shfl((int)pC1, src0, 64), d0s = __shfl((int)pD1, src0, 64);
        int a1s = __shfl((int)pA1, src1, 64), b1s = __shfl((int)pB1, src1, 64);
        int c1s = __shfl((int)pC1, src1, 64), d1s = __shfl((int)pD1, src1, 64);
        pu1.u[0] = lo ? a0s : c0s;
        pu1.u[1] = lo ? b0s : d0s;
        pu1.u[2] = lo ? a1s : c1s;
        pu1.u[3] = lo ? b1s : d1s;
      }
      short8 pa0 = pu0.s, pa1 = pu1.s;
      // ---- O += P V; vf loaded once, used by both strips ----
#pragma unroll
      for (int dq = 0; dq < 16; ++dq) {
        short8 vf = *reinterpret_cast<const short8*>(
            vt + (16 * dq + c16) * VSTR + 8 * (g ^ (dq & 3)));
        oa0[dq] = __builtin_amdgcn_mfma_f32_16x16x32_bf16(pa0, vf, oa0[dq], 0, 0, 0);
        oa1[dq] = __builtin_amdgcn_mfma_f32_16x16x32_bf16(pa1, vf, oa1[dq], 0, 0, 0);
      }
    }
    __syncthreads();  // drains vmcnt (next tile landed) + all LDS reads done
  }

  // ---- rowsum reduce across g-groups (same c16) ----
  rss0 += __shfl_xor(rss0, 16);
  rss0 += __shfl_xor(rss0, 32);
  rss1 += __shfl_xor(rss1, 16);
  rss1 += __shfl_xor(rss1, 32);

  float* rsP = (p == 0) ? rs0 : (p == 1) ? rs1 : (p == 2) ? rs2 : rs3;
  if (l < 16) {
    rsP[hd * S_ + iw0 + l] = rss0;
    rsP[hd * S_ + iw1 + l] = rss1;
  }

  short* po = (p == 0) ? po0 : (p == 1) ? po1 : (p == 2) ? po2 : po3;
#pragma unroll
  for (int dq = 0; dq < 16; ++dq)
#pragma unroll
    for (int r = 0; r < 4; ++r) {
      po[((size_t)(hd * S_ + iw0 + 4 * g + r)) * DH_ + dq * 16 + c16] =
          f2bf(oa0[dq][r]);
      po[((size_t)(hd * S_ + iw1 + 4 * g + r)) * DH_ + dq * 16 + c16] =
          f2bf(oa1[dq][r]);
    }
}

// ---------------------------------------------------------------------------
// Kernel 4: combine 4 bf16 partials -> normalizer + layernorm -> out (f32).
// ---------------------------------------------------------------------------
__global__ __launch_bounds__(256) void combine_kernel(
    const short* __restrict__ po0, const short* __restrict__ po1,
    const short* __restrict__ po2, const short* __restrict__ po3,
    const float* __restrict__ rs0, const float* __restrict__ rs1,
    const float* __restrict__ rs2, const float* __restrict__ rs3,
    const float* __restrict__ fl_arr, const float* __restrict__ scale,
    float* __restrict__ out) {
  int ridx = blockIdx.x * 4 + (threadIdx.x >> 6);
  int lane = threadIdx.x & 63;
  int hd = ridx >> 11, i = ridx & 2047;
  int b = hd >> 2, nh = hd & 3;

  size_t poi = ((size_t)(hd * S_ + i)) * DH_ + lane * 4;
  short4v a4 = *reinterpret_cast<const short4v*>(po0 + poi);
  short4v b4 = *reinterpret_cast<const short4v*>(po1 + poi);
  short4v c4 = *reinterpret_cast<const short4v*>(po2 + poi);
  short4v d4 = *reinterpret_cast<const short4v*>(po3 + poi);

  float rsum = rs0[hd * S_ + i] + rs1[hd * S_ + i] + rs2[hd * S_ + i] +
               rs3[hd * S_ + i];
  float o0 = bf2f(a4[0]) + bf2f(b4[0]) + bf2f(c4[0]) + bf2f(d4[0]);
  float o1 = bf2f(a4[1]) + bf2f(b4[1]) + bf2f(c4[1]) + bf2f(d4[1]);
  float o2 = bf2f(a4[2]) + bf2f(b4[2]) + bf2f(c4[2]) + bf2f(d4[2]);
  float o3 = bf2f(a4[3]) + bf2f(b4[3]) + bf2f(c4[3]) + bf2f(d4[3]);

  float fl = fl_arr[(size_t)hd * S_ + i];
  float inv = 1.f / (fmaxf(fabsf(rsum), fl) + 1e-6f);
  o0 *= inv; o1 *= inv; o2 *= inv; o3 *= inv;

  float s1 = o0 + o1 + o2 + o3;
  float s2 = o0 * o0 + o1 * o1 + o2 * o2 + o3 * o3;
#pragma unroll
  for (int m = 1; m < 64; m <<= 1) {
    s1 += __shfl_xor(s1, m);
    s2 += __shfl_xor(s2, m);
  }
  float mean = s1 * (1.f / DH_);
  float var = s2 * (1.f / DH_) - mean * mean;
  float rstd = rsqrtf(var + 1e-6f);

  const float* scp = scale + nh * DH_ + lane * 4;
  float4 res;
  res.x = (o0 - mean) * rstd * scp[0];
  res.y = (o1 - mean) * rstd * scp[1];
  res.z = (o2 - mean) * rstd * scp[2];
  res.w = (o3 - mean) * rstd * scp[3];
  float* op = out + ((size_t)b * S_ + i) * H_ + nh * DH_ + lane * 4;
  *reinterpret_cast<float4*>(op) = res;
}

// ---------------------------------------------------------------------------
extern "C" void kernel_launch(void* const* d_in, const int* in_sizes, int n_in,
                              void* d_out, int out_size, void* d_ws,
                              size_t ws_size, hipStream_t stream) {
  const float* q   = (const float*)d_in[0];
  const float* k   = (const float*)d_in[1];
  const float* v   = (const float*)d_in[2];
  const float* igk = (const float*)d_in[3];
  const float* igb = (const float*)d_in[4];
  const float* fgk = (const float*)d_in[5];
  const float* fgb = (const float*)d_in[6];
  const float* scl = (const float*)d_in[7];
  float* out = (float*)d_out;

  const size_t seq = (size_t)B_ * NH_ * S_;  // 16384
  const size_t pon = (size_t)8 * 2048 * 256; // elements per partial buffer
  float* ws = (float*)d_ws;
  float* ig_pre = ws;
  float* lsf    = ws + seq;
  float* a_arr  = ws + 2 * seq;
  float* M_arr  = ws + 3 * seq;
  float* fl_arr = ws + 4 * seq;
  float* rs0    = ws + 5 * seq;
  float* rs1    = ws + 6 * seq;
  float* rs2    = ws + 7 * seq;
  float* rs3    = ws + 8 * seq;
  char*  kpack  = (char*)(ws + 9 * seq);                 // 8 MB
  char*  vpack  = kpack + (size_t)8 * 64 * KTILE_BYTES;  // 9.4 MB
  short* po0    = (short*)(vpack + (size_t)8 * 64 * VTILE_BYTES);
  short* po1    = po0 + pon;
  short* po2    = po1 + pon;
  short* po3    = po2 + pon;   // bf16 partials: 4 x 8.4 MB; total ~52 MB

  gates_pack_kernel<<<(B_ * S_) / 4, 256, 0, stream>>>(
      q, k, v, igk, igb, fgk, fgb, ig_pre, lsf, kpack, vpack);
  scan_kernel<<<B_ * NH_, 64, 0, stream>>>(ig_pre, lsf, a_arr, M_arr, fl_arr);
  mlstm_mfma<<<512, 256, 0, stream>>>(q, a_arr, M_arr, kpack, vpack,
                                      po0, po1, po2, po3,
                                      rs0, rs1, rs2, rs3);
  combine_kernel<<<B_ * NH_ * S_ / 4, 256, 0, stream>>>(
      po0, po1, po2, po3, rs0, rs1, rs2, rs3, fl_arr, scl, out);
}